// Round 5
// baseline (178.015 us; speedup 1.0000x reference)
//
#include <hip/hip_runtime.h>
#include <hip/hip_bf16.h>

#define BB   16
#define CIN  256
#define TN   4096
#define LOUT 4110
#define FTS  4224   // first_t per-batch stride (ints)

typedef __attribute__((ext_vector_type(8))) short s16x8;
typedef __attribute__((ext_vector_type(4))) float f32x4;

// ---------------- workspace layout (bytes) ----------------
// featT  bf16 [B][T][256]        0          (33554432)
// wBpk   bf16 fragment-packed    33554432   (262144)  -> 33816576
// bnp    float4[256]             33816576   (4096)    -> 33820672
// wp0T   f32  [62][32]           33820672   (8192)    -> 33828864
// wp1M   bf16 frag-packed p1     33828864   (30720)   -> 33859584
// wp2M   bf16 frag-packed p2     33859584   (15360)   -> 33874944
// bnp0   float2[32]              33874944   (256)     -> 33875200
// bnp1   float2[32]              33875200   (256)     -> 33875456
// xx     f32  [B][T]             33890304
// wts    f32  [B][T]             34152448
// mvr    f32  [B][T]             34414592
// poses  f32  [B][T]             34676736
// firstT int  [B][4224]          34938880   (end 35209216)
// xT bf16 [B][T][256] lives in d_out (33.5MB < 67.3MB; K4 rewrites all of d_out)

// ======================= K0: weight prep =======================
__global__ __launch_bounds__(256) void k0_prep(
    const float* __restrict__ conv1_w, const float* __restrict__ p0_w,
    const float* __restrict__ p1_w, const float* __restrict__ p2_w,
    const float* __restrict__ bn1_g, const float* __restrict__ bn1_b,
    const float* __restrict__ bn1_m, const float* __restrict__ bn1_v,
    const float* __restrict__ p0_b, const float* __restrict__ p0g,
    const float* __restrict__ p0bb, const float* __restrict__ p0m,
    const float* __restrict__ p0v,
    const float* __restrict__ p1_b, const float* __restrict__ p1g,
    const float* __restrict__ p1bb, const float* __restrict__ p1m,
    const float* __restrict__ p1v,
    short* __restrict__ wBpk, float4* __restrict__ bnp,
    float* __restrict__ wp0T, short* __restrict__ wp1M,
    short* __restrict__ wp2M, float2* __restrict__ bnp0,
    float2* __restrict__ bnp1) {
  int bid = blockIdx.x, tid = threadIdx.x;
  if (bid < 512) {
    // wBpk flat: ((n16*8 + ks)*64 + l)*8 + i ; value = Wpacked[n16*16+(l&15)][ks*32+(l>>4)*8+i]
    int e = bid * 256 + tid;               // 0..131071
    int i = e & 7, l = (e >> 3) & 63, ks = (e >> 9) & 7, n16 = e >> 12;
    int n = n16 * 16 + (l & 15);           // packed col 0..511
    int j = n & 63;
    int co = (j < 32) ? ((n >> 6) * 32 + j) : (256 + (n >> 6) * 32 + (j - 32));
    int ci = ks * 32 + (l >> 4) * 8 + i;
    __hip_bfloat16 hv = __float2bfloat16(conv1_w[co * 256 + ci]);
    wBpk[e] = *(short*)&hv;
  } else {
    int idx = (bid - 512) * 256 + tid;     // 0..15359
    if (idx < 1984) {
      int ch = idx & 31, rem = idx >> 5;
      int ic = rem / 31, k = rem % 31;
      wp0T[idx] = p0_w[(ch * 2 + ic) * 31 + k];
    }
    {  // wp1M: idx bits [0:3)=i, [3:9)=l, [9)=nf, [10:..)=koff
      int i = idx & 7, l = (idx >> 3) & 63, nf = (idx >> 9) & 1, koff = idx >> 10;
      int ch = nf * 16 + (l & 15), ic = (l >> 4) * 8 + i;
      __hip_bfloat16 hv = __float2bfloat16(p1_w[(ch * 32 + ic) * 15 + koff]);
      wp1M[idx] = *(short*)&hv;
    }
    if (idx < 7680) {  // wp2M: bits [0:3)=i, [3:9)=l, [9:..)=koff
      int i = idx & 7, l = (idx >> 3) & 63, koff = idx >> 9;
      int n = l & 15, ic = (l >> 4) * 8 + i;
      float v = (n < 2) ? p2_w[(n * 32 + ic) * 15 + koff] : 0.f;
      __hip_bfloat16 hv = __float2bfloat16(v);
      wp2M[idx] = *(short*)&hv;
    }
    if (idx < 32) {
      int ch = idx;
      float sc = p0g[ch] * rsqrtf(p0v[ch] + 1e-5f);
      bnp0[ch] = make_float2(sc, (p0_b[ch] - p0m[ch]) * sc + p0bb[ch]);
    }
    if (idx >= 32 && idx < 64) {
      int ch = idx - 32;
      float sc = p1g[ch] * rsqrtf(p1v[ch] + 1e-5f);
      bnp1[ch] = make_float2(sc, (p1_b[ch] - p1m[ch]) * sc + p1bb[ch]);
    }
    if (idx < 256) {
      int c = idx;
      float sa = bn1_g[c] * rsqrtf(bn1_v[c] + 1e-3f);
      float ba = bn1_b[c] - bn1_m[c] * sa;
      float sg = bn1_g[c + 256] * rsqrtf(bn1_v[c + 256] + 1e-3f);
      float bg = bn1_b[c + 256] - bn1_m[c + 256] * sg;
      bnp[c] = make_float4(sa, ba, sg, bg);
    }
  }
}

// ============ K0b: transpose+cvt x -> xT bf16 [t][ci], + xx (f32 exact) ============
__global__ __launch_bounds__(256) void k0b_tr(
    const float* __restrict__ x, const float* __restrict__ w1x1,
    short* __restrict__ xT, float* __restrict__ xx) {
  int t0 = blockIdx.x * 64;
  int b = blockIdx.y;
  __shared__ float ls[64][129];
  int tid = threadIdx.x;
  const float* xb = x + (size_t)b * (CIN * TN);
  float xacc = 0.f;
  for (int half = 0; half < 2; ++half) {
    if (half) __syncthreads();
#pragma unroll
    for (int s = 0; s < 8; ++s) {
      int idx = tid + s * 256;             // 0..2047
      int ci = idx >> 4, tc = idx & 15;
      float4 v = *(const float4*)(xb + (size_t)(half * 128 + ci) * TN + t0 + tc * 4);
      ls[tc * 4 + 0][ci] = v.x;
      ls[tc * 4 + 1][ci] = v.y;
      ls[tc * 4 + 2][ci] = v.z;
      ls[tc * 4 + 3][ci] = v.w;
    }
    __syncthreads();
    if (tid < 64) {
#pragma unroll 4
      for (int k = 0; k < 128; ++k)
        xacc = fmaf(ls[tid][k], w1x1[half * 128 + k], xacc);
    }
#pragma unroll
    for (int s = 0; s < 4; ++s) {
      int o = tid + s * 256;               // 0..1023
      int ci8 = o & 15, t = o >> 4;
      s16x8 pk;
#pragma unroll
      for (int i = 0; i < 8; ++i) {
        __hip_bfloat16 hv = __float2bfloat16(ls[t][ci8 * 8 + i]);
        pk[i] = *(short*)&hv;
      }
      *(s16x8*)(xT + ((size_t)(b * TN) + t0 + t) * 256 + half * 128 + ci8 * 8) = pk;
    }
  }
  if (tid < 64) xx[b * TN + t0 + tid] = xacc;
}

// ========== K1: bf16 MFMA GEMM + BN + GLU ==========
__global__ __launch_bounds__(256) void k1_mfma(
    const short* __restrict__ xT, const short* __restrict__ wBpk,
    const float4* __restrict__ bnp, __hip_bfloat16* __restrict__ featT) {
  int f = blockIdx.x + 4 * (blockIdx.y + 32 * blockIdx.z);  // 0..2047
  int w = (f & 7) * 256 + (f >> 3);        // XCD-bijective: A-tile sharers on one XCD
  int nblk = w & 3, ty = (w >> 2) & 31, b = w >> 7;
  int t0 = ty * 128;
  int tid = threadIdx.x;
  int l = tid & 63, wv = tid >> 6;
  int wm = wv & 1, wn = wv >> 1;
  int tb = t0 + wm * 64;
  int nb16 = nblk * 8 + wn * 4;            // n16 base (4 frags of 16 cols)

  f32x4 acc[4][4];
#pragma unroll
  for (int i = 0; i < 4; ++i)
#pragma unroll
    for (int j = 0; j < 4; ++j) acc[i][j] = (f32x4){0.f, 0.f, 0.f, 0.f};

  const short* arow = xT + ((size_t)(b * TN) + tb + (l & 15)) * 256 + (l >> 4) * 8;
  const short* wrow = wBpk + l * 8;

#pragma unroll 2
  for (int ks = 0; ks < 8; ++ks) {
    s16x8 af[4], bf[4];
#pragma unroll
    for (int mf = 0; mf < 4; ++mf)
      af[mf] = *(const s16x8*)(arow + mf * 16 * 256 + ks * 32);
#pragma unroll
    for (int nf = 0; nf < 4; ++nf)
      bf[nf] = *(const s16x8*)(wrow + (size_t)(nb16 + nf) * 4096 + ks * 512);
#pragma unroll
    for (int mf = 0; mf < 4; ++mf)
#pragma unroll
      for (int nf = 0; nf < 4; ++nf)
        acc[mf][nf] = __builtin_amdgcn_mfma_f32_16x16x32_bf16(
            af[mf], bf[nf], acc[mf][nf], 0, 0, 0);
  }

  // epilogue: BN + GLU (packed col j pairs with j+32 -> frag nf vs nf+2, same lane)
  int cb = (nblk * 2 + wn) * 32;
#pragma unroll
  for (int nf = 0; nf < 2; ++nf) {
    float4 bn = bnp[cb + nf * 16 + (l & 15)];
    int c = cb + nf * 16 + (l & 15);
#pragma unroll
    for (int mf = 0; mf < 4; ++mf) {
#pragma unroll
      for (int r = 0; r < 4; ++r) {
        float a = acc[mf][nf][r], g = acc[mf][nf + 2][r];
        float av = fmaf(a, bn.x, bn.y);
        float gv = fmaf(g, bn.z, bn.w);
        float fv = av / (1.f + __expf(-gv));
        int t = tb + mf * 16 + (l >> 4) * 4 + r;
        featT[((size_t)b * TN + t) * 256 + c] = __float2bfloat16(fv);
      }
    }
  }
}

// ========== K2: fused predictor; p0 = VALU f32, p1/p2 = MFMA bf16 ==========
// grid (32 t-tiles of 128, 16 b), 512 thr = 8 waves.
__global__ __launch_bounds__(512) void k2_pred(
    const float* __restrict__ xx,
    const float* __restrict__ wp0T, const float2* __restrict__ bnp0,
    const short* __restrict__ wp1M, const float2* __restrict__ bnp1,
    const short* __restrict__ wp2M, const float* __restrict__ p2_b,
    const float* __restrict__ norm_mean,
    float* __restrict__ wts, float* __restrict__ mvr) {
  int t0 = blockIdx.x * 128;
  int b = blockIdx.y;
  __shared__ float xin[2][192];     // t = t0-29+q, valid q<186
  __shared__ short h0T[160 * 40];
  __shared__ short h1T[144 * 40];
  int tid = threadIdx.x;
  for (int q = tid; q < 192; q += 512) {
    int t = t0 - 29 + q;
    float v = (q < 186 && t >= 0 && t < TN) ? xx[b * TN + t] : 0.f;
    xin[0][q] = v;
    xin[1][q] = v * v;
  }
  __syncthreads();
  {  // p0: K=31, 2 in-ch, f32 VALU; thread (ch, tq) -> 12 outputs
    int ch = tid & 31, tq = tid >> 5;    // tq 0..15
    int i0 = tq * 12;
    if (i0 < 156) {
      float2 bb0 = bnp0[ch];
      float a0[12];
#pragma unroll
      for (int j = 0; j < 12; ++j) a0[j] = 0.f;
#pragma unroll
      for (int ic = 0; ic < 2; ++ic) {
        float rr[44];
#pragma unroll
        for (int q = 0; q < 11; ++q) {
          float4 t4 = *(const float4*)(&xin[ic][i0 + q * 4]);
          rr[q * 4 + 0] = t4.x; rr[q * 4 + 1] = t4.y;
          rr[q * 4 + 2] = t4.z; rr[q * 4 + 3] = t4.w;
        }
#pragma unroll
        for (int k = 0; k < 31; ++k) {
          float w = wp0T[(ic * 31 + k) * 32 + ch];
#pragma unroll
          for (int j = 0; j < 12; ++j) a0[j] = fmaf(w, rr[j + k], a0[j]);
        }
      }
#pragma unroll
      for (int j = 0; j < 12; ++j) {
        int i = i0 + j;
        if (i < 156) {
          float v = a0[j] * bb0.x + bb0.y;
          float h = v / (1.f + __expf(-v));
          __hip_bfloat16 hv = __float2bfloat16(h);
          h0T[i * 40 + ch] = *(short*)&hv;
        }
      }
    }
    if (tid < 128) h0T[(156 + (tid >> 5)) * 40 + (tid & 31)] = 0;  // zero pad rows
  }
  __syncthreads();
  int l = tid & 63, wv = tid >> 6;
  int lrow = l & 15, lk8 = (l >> 4) * 8;
  {  // p1: 15 shifted MFMAs (K=32=ic); 9 m-frags over 8 waves (wave0 gets 2)
    f32x4 acc[2][2];
#pragma unroll
    for (int i = 0; i < 2; ++i)
#pragma unroll
      for (int j = 0; j < 2; ++j) acc[i][j] = (f32x4){0.f, 0.f, 0.f, 0.f};
    int nmf = (wv == 0) ? 2 : 1;
    for (int koff = 0; koff < 15; ++koff) {
      const short* bp = wp1M + koff * 1024;
      s16x8 bf0 = *(const s16x8*)(bp + l * 8);
      s16x8 bf1 = *(const s16x8*)(bp + 512 + l * 8);
      for (int mi = 0; mi < nmf; ++mi) {
        int mf = (mi == 0) ? wv : 8;
        s16x8 af = *(const s16x8*)(&h0T[(mf * 16 + koff + lrow) * 40 + lk8]);
        acc[mi][0] = __builtin_amdgcn_mfma_f32_16x16x32_bf16(af, bf0, acc[mi][0], 0, 0, 0);
        acc[mi][1] = __builtin_amdgcn_mfma_f32_16x16x32_bf16(af, bf1, acc[mi][1], 0, 0, 0);
      }
    }
    for (int mi = 0; mi < nmf; ++mi) {
      int mf = (mi == 0) ? wv : 8;
#pragma unroll
      for (int nf = 0; nf < 2; ++nf) {
        int ch = nf * 16 + lrow;
        float2 bb = bnp1[ch];
#pragma unroll
        for (int r = 0; r < 4; ++r) {
          int row = mf * 16 + (l >> 4) * 4 + r;
          float v = acc[mi][nf][r] * bb.x + bb.y;
          float h = v / (1.f + __expf(-v));
          __hip_bfloat16 hv = __float2bfloat16(h);
          h1T[row * 40 + ch] = *(short*)&hv;
        }
      }
    }
  }
  __syncthreads();
  {  // p2: 15 shifted MFMAs, N=16 (2 cols used); 8 m-frags = 1/wave
    f32x4 acc2 = (f32x4){0.f, 0.f, 0.f, 0.f};
    for (int koff = 0; koff < 15; ++koff) {
      s16x8 bf = *(const s16x8*)(wp2M + koff * 512 + l * 8);
      s16x8 af = *(const s16x8*)(&h1T[(wv * 16 + koff + lrow) * 40 + lk8]);
      acc2 = __builtin_amdgcn_mfma_f32_16x16x32_bf16(af, bf, acc2, 0, 0, 0);
    }
    int ch = lrow;
    if (ch < 2) {
      float pb = p2_b[ch];
      float nm = norm_mean[0];
#pragma unroll
      for (int r = 0; r < 4; ++r) {
        int t = t0 + wv * 16 + (l >> 4) * 4 + r;
        float a = acc2[r] + pb;
        float s = 1.f / (1.f + __expf(-a));
        if (ch == 0) wts[b * TN + t] = s;
        else         mvr[b * TN + t] = s * nm;
      }
    }
  }
}

// ========== K3: per-batch renorm + cumsum + first_t ==========
__global__ __launch_bounds__(256) void k3_scan(const float* __restrict__ mvr,
                                               float* __restrict__ poses,
                                               int* __restrict__ firstT) {
  int b = blockIdx.x, tid = threadIdx.x;
  __shared__ float csum[256];
  __shared__ int shlast;
  float v[16];
  const float* src = mvr + b * TN + tid * 16;
  float run = 0.f;
#pragma unroll
  for (int j = 0; j < 16; ++j) { run += src[j]; v[j] = run; }
  csum[tid] = run;
  __syncthreads();
  for (int off = 1; off < 256; off <<= 1) {
    float tv = (tid >= off) ? csum[tid - off] : 0.f;
    __syncthreads();
    csum[tid] += tv;
    __syncthreads();
  }
  float incl = csum[tid];
  float total = csum[255];
  float excl = incl - run;
  __syncthreads();
  float rn = total * (1.0f / 4096.0f);
  float inv = (rn > 1.0f) ? 1.0f / rn : 1.0f;
  float p16[16];
  float* pd = poses + b * TN + tid * 16;
#pragma unroll
  for (int j = 0; j < 16; ++j) { p16[j] = (excl + v[j]) * inv; pd[j] = p16[j]; }
  csum[tid] = p16[15];
  __syncthreads();
  int* ft = firstT + b * FTS;
  int prevf = (tid == 0) ? -1 : min((int)floorf(csum[tid - 1]), 4220);
  int f = prevf;
#pragma unroll
  for (int j = 0; j < 16; ++j) {
    f = min((int)floorf(p16[j]), 4220);
    for (int l = prevf + 1; l <= f; ++l) ft[l] = tid * 16 + j;
    prevf = f;
  }
  if (tid == 255) shlast = f;
  __syncthreads();
  for (int l = shlast + 1 + tid; l < FTS; l += 256) ft[l] = TN;
}

// ========== K4: gather pool v2 — register running-sums, 64-row tiles ==========
// grid (65, 16) -> XCD-chunked swizzle (1040 = 8*130). 256 thr (one per channel).
// fi monotone (moves<=1 => floor advances <=1) and wave-uniform: keep S_lo(row cur)
// and S_hi(row cur+1) in registers; flush to LDS once per row-advance; dump tile.
__global__ __launch_bounds__(256) void k4_gather(
    const __hip_bfloat16* __restrict__ featT, const float* __restrict__ wts,
    const float* __restrict__ poses, const int* __restrict__ firstT,
    float* __restrict__ out) {
  int d = blockIdx.x + 65 * blockIdx.y;          // dispatch index, 0..1039
  int w = (d & 7) * 130 + (d >> 3);              // XCD k gets tiles [k*130,(k+1)*130)
  int lx = w % 65, b = w / 65;
  int l0 = lx * 64;
  __shared__ float acc[64][259];                 // 259: dump reads 2-way free
  int tid = threadIdx.x;
  for (int i = tid; i < 64 * 259; i += 256) ((float*)acc)[i] = 0.f;
  const int* ft = firstT + b * FTS;
  int ts = (l0 == 0) ? 0 : ft[l0 - 1];
  int te = ft[l0 + 64];
  __syncthreads();
  int c = tid;
  if (ts < te) {
    const float* pp = poses + b * TN;
    const float* wp = wts + b * TN;
    const __hip_bfloat16* fp = featT + (size_t)(b * TN) * 256 + c;
    float p_cur = pp[ts];
    float w_cur = wp[ts];
    float f_cur = __bfloat162float(fp[(size_t)ts * 256]);
    float S_lo = 0.f, S_hi = 0.f;
    int cur = (int)floorf(p_cur);
    for (int t = ts; t < te; ++t) {
      float p_nxt = 0.f, w_nxt = 0.f, f_nxt = 0.f;
      if (t + 1 < te) {                          // prefetch next iter
        p_nxt = pp[t + 1];
        w_nxt = wp[t + 1];
        f_nxt = __bfloat162float(fp[(size_t)(t + 1) * 256]);
      }
      int fi = (int)floorf(p_cur);
      if (fi < cur) fi = cur;                    // FP scan-boundary wobble guard
      if (fi != cur) {                           // wave-uniform advance
        int r = cur - l0;
        if (r >= 0 && r < 64) acc[r][c] = S_lo;  // row cur is final
        if (fi == cur + 1) {
          S_lo = S_hi;
        } else {                                 // jump (only possible at init)
          int r2 = cur + 1 - l0;
          if (r2 >= 0 && r2 < 64) acc[r2][c] = S_hi;
          S_lo = 0.f;
        }
        S_hi = 0.f;
        cur = fi;
      }
      float w2 = p_cur - (float)fi;
      float fw = f_cur * w_cur;
      S_lo = fmaf(1.f - w2, fw, S_lo);
      S_hi = fmaf(w2, fw, S_hi);
      p_cur = p_nxt; w_cur = w_nxt; f_cur = f_nxt;
    }
    int r = cur - l0;                            // final rows
    if (r >= 0 && r < 64) acc[r][c] = S_lo;
    int r2 = cur + 1 - l0;
    if (r2 >= 0 && r2 < 64) acc[r2][c] = S_hi;
  }
  __syncthreads();
  // dump: wave covers 64 consecutive l of one c-row -> 256B contiguous stores
  for (int i = tid; i < 64 * 256; i += 256) {
    int c2 = i >> 6, r = i & 63;
    int l = l0 + r;
    if (l < LOUT) out[((size_t)b * 256 + c2) * LOUT + l] = acc[r][c2];
  }
}

// ======================= launch =======================
extern "C" void kernel_launch(void* const* d_in, const int* in_sizes, int n_in,
                              void* d_out, int out_size, void* d_ws, size_t ws_size,
                              hipStream_t stream) {
  const float* x       = (const float*)d_in[0];
  const float* conv1_w = (const float*)d_in[1];
  const float* bn1_g   = (const float*)d_in[2];
  const float* bn1_b   = (const float*)d_in[3];
  const float* bn1_m   = (const float*)d_in[4];
  const float* bn1_v   = (const float*)d_in[5];
  const float* w1x1    = (const float*)d_in[6];
  const float* p0_w    = (const float*)d_in[7];
  const float* p0_b    = (const float*)d_in[8];
  const float* p0g     = (const float*)d_in[9];
  const float* p0bb    = (const float*)d_in[10];
  const float* p0m     = (const float*)d_in[11];
  const float* p0v     = (const float*)d_in[12];
  const float* p1_w    = (const float*)d_in[13];
  const float* p1_b    = (const float*)d_in[14];
  const float* p1g     = (const float*)d_in[15];
  const float* p1bb    = (const float*)d_in[16];
  const float* p1m     = (const float*)d_in[17];
  const float* p1v     = (const float*)d_in[18];
  const float* p2_w    = (const float*)d_in[19];
  const float* p2_b    = (const float*)d_in[20];
  const float* nmean   = (const float*)d_in[21];

  char* ws = (char*)d_ws;
  __hip_bfloat16* featT = (__hip_bfloat16*)ws;
  short* wBpk   = (short*)(ws + 33554432);
  float4* bnp   = (float4*)(ws + 33816576);
  float* wp0T   = (float*)(ws + 33820672);
  short* wp1M   = (short*)(ws + 33828864);
  short* wp2M   = (short*)(ws + 33859584);
  float2* bnp0  = (float2*)(ws + 33874944);
  float2* bnp1  = (float2*)(ws + 33875200);
  float* xx     = (float*)(ws + 33890304);
  float* wts    = (float*)(ws + 34152448);
  float* mvr    = (float*)(ws + 34414592);
  float* poses  = (float*)(ws + 34676736);
  int*   firstT = (int*)  (ws + 34938880);
  float* out    = (float*)d_out;
  short* xT     = (short*)d_out;   // scratch; K4 rewrites every element of d_out

  k0_prep<<<dim3(572), dim3(256), 0, stream>>>(
      conv1_w, p0_w, p1_w, p2_w, bn1_g, bn1_b, bn1_m, bn1_v,
      p0_b, p0g, p0bb, p0m, p0v, p1_b, p1g, p1bb, p1m, p1v,
      wBpk, bnp, wp0T, wp1M, wp2M, bnp0, bnp1);
  k0b_tr<<<dim3(64, 16), dim3(256), 0, stream>>>(x, w1x1, xT, xx);
  k1_mfma<<<dim3(4, 32, 16), dim3(256), 0, stream>>>(xT, wBpk, bnp, featT);
  k2_pred<<<dim3(32, 16), dim3(512), 0, stream>>>(xx, wp0T, bnp0, wp1M, bnp1,
                                                  wp2M, p2_b, nmean, wts, mvr);
  k3_scan<<<dim3(16), dim3(256), 0, stream>>>(mvr, poses, firstT);
  k4_gather<<<dim3(65, 16), dim3(256), 0, stream>>>(featT, wts, poses, firstT, out);
}

// Round 6
// 123.045 us; speedup vs baseline: 1.4468x; 1.4468x over previous
//
#include <hip/hip_runtime.h>
#include <hip/hip_bf16.h>

#define BB   16
#define CIN  256
#define TN   4096
#define LOUT 4110
#define FTS  4224   // first_t per-batch stride (ints)

typedef __attribute__((ext_vector_type(8))) short s16x8;
typedef __attribute__((ext_vector_type(4))) float f32x4;

// ---------------- workspace layout (bytes) ----------------
// featT  bf16 [B][T][256]        0          (33554432)
// wBpk   bf16 fragment-packed    33554432   (262144)  -> 33816576
// bnp    float4[256]             33816576   (4096)    -> 33820672
// wp0T   f32  [62][32]           33820672   (8192)    -> 33828864
// wp1M   bf16 frag-packed p1     33828864   (30720)   -> 33859584
// wp2M   bf16 frag-packed p2     33859584   (15360)   -> 33874944
// bnp0   float2[32]              33874944   (256)     -> 33875200
// bnp1   float2[32]              33875200   (256)     -> 33875456
// xx     f32  [B][T]             33890304
// wts    f32  [B][T]             34152448
// mvr    f32  [B][T]             34414592
// poses  f32  [B][T]             34676736
// firstT int  [B][4224]          34938880   (end 35209216)
// xT bf16 [B][T][256] lives in d_out (33.5MB < 67.3MB; K4 rewrites all of d_out)

// ======================= K0: weight prep =======================
__global__ __launch_bounds__(256) void k0_prep(
    const float* __restrict__ conv1_w, const float* __restrict__ p0_w,
    const float* __restrict__ p1_w, const float* __restrict__ p2_w,
    const float* __restrict__ bn1_g, const float* __restrict__ bn1_b,
    const float* __restrict__ bn1_m, const float* __restrict__ bn1_v,
    const float* __restrict__ p0_b, const float* __restrict__ p0g,
    const float* __restrict__ p0bb, const float* __restrict__ p0m,
    const float* __restrict__ p0v,
    const float* __restrict__ p1_b, const float* __restrict__ p1g,
    const float* __restrict__ p1bb, const float* __restrict__ p1m,
    const float* __restrict__ p1v,
    short* __restrict__ wBpk, float4* __restrict__ bnp,
    float* __restrict__ wp0T, short* __restrict__ wp1M,
    short* __restrict__ wp2M, float2* __restrict__ bnp0,
    float2* __restrict__ bnp1) {
  int bid = blockIdx.x, tid = threadIdx.x;
  if (bid < 512) {
    // wBpk flat: ((n16*8 + ks)*64 + l)*8 + i ; value = Wpacked[n16*16+(l&15)][ks*32+(l>>4)*8+i]
    int e = bid * 256 + tid;               // 0..131071
    int i = e & 7, l = (e >> 3) & 63, ks = (e >> 9) & 7, n16 = e >> 12;
    int n = n16 * 16 + (l & 15);           // packed col 0..511
    int j = n & 63;
    int co = (j < 32) ? ((n >> 6) * 32 + j) : (256 + (n >> 6) * 32 + (j - 32));
    int ci = ks * 32 + (l >> 4) * 8 + i;
    __hip_bfloat16 hv = __float2bfloat16(conv1_w[co * 256 + ci]);
    wBpk[e] = *(short*)&hv;
  } else {
    int idx = (bid - 512) * 256 + tid;     // 0..15359
    if (idx < 1984) {
      int ch = idx & 31, rem = idx >> 5;
      int ic = rem / 31, k = rem % 31;
      wp0T[idx] = p0_w[(ch * 2 + ic) * 31 + k];
    }
    {  // wp1M: idx bits [0:3)=i, [3:9)=l, [9)=nf, [10:..)=koff
      int i = idx & 7, l = (idx >> 3) & 63, nf = (idx >> 9) & 1, koff = idx >> 10;
      int ch = nf * 16 + (l & 15), ic = (l >> 4) * 8 + i;
      __hip_bfloat16 hv = __float2bfloat16(p1_w[(ch * 32 + ic) * 15 + koff]);
      wp1M[idx] = *(short*)&hv;
    }
    if (idx < 7680) {  // wp2M: bits [0:3)=i, [3:9)=l, [9:..)=koff
      int i = idx & 7, l = (idx >> 3) & 63, koff = idx >> 9;
      int n = l & 15, ic = (l >> 4) * 8 + i;
      float v = (n < 2) ? p2_w[(n * 32 + ic) * 15 + koff] : 0.f;
      __hip_bfloat16 hv = __float2bfloat16(v);
      wp2M[idx] = *(short*)&hv;
    }
    if (idx < 32) {
      int ch = idx;
      float sc = p0g[ch] * rsqrtf(p0v[ch] + 1e-5f);
      bnp0[ch] = make_float2(sc, (p0_b[ch] - p0m[ch]) * sc + p0bb[ch]);
    }
    if (idx >= 32 && idx < 64) {
      int ch = idx - 32;
      float sc = p1g[ch] * rsqrtf(p1v[ch] + 1e-5f);
      bnp1[ch] = make_float2(sc, (p1_b[ch] - p1m[ch]) * sc + p1bb[ch]);
    }
    if (idx < 256) {
      int c = idx;
      float sa = bn1_g[c] * rsqrtf(bn1_v[c] + 1e-3f);
      float ba = bn1_b[c] - bn1_m[c] * sa;
      float sg = bn1_g[c + 256] * rsqrtf(bn1_v[c + 256] + 1e-3f);
      float bg = bn1_b[c + 256] - bn1_m[c + 256] * sg;
      bnp[c] = make_float4(sa, ba, sg, bg);
    }
  }
}

// ============ K0b: transpose+cvt x -> xT bf16 [t][ci], + xx (f32 exact) ============
__global__ __launch_bounds__(256) void k0b_tr(
    const float* __restrict__ x, const float* __restrict__ w1x1,
    short* __restrict__ xT, float* __restrict__ xx) {
  int t0 = blockIdx.x * 64;
  int b = blockIdx.y;
  __shared__ float ls[64][129];
  int tid = threadIdx.x;
  const float* xb = x + (size_t)b * (CIN * TN);
  float xacc = 0.f;
  for (int half = 0; half < 2; ++half) {
    if (half) __syncthreads();
#pragma unroll
    for (int s = 0; s < 8; ++s) {
      int idx = tid + s * 256;             // 0..2047
      int ci = idx >> 4, tc = idx & 15;
      float4 v = *(const float4*)(xb + (size_t)(half * 128 + ci) * TN + t0 + tc * 4);
      ls[tc * 4 + 0][ci] = v.x;
      ls[tc * 4 + 1][ci] = v.y;
      ls[tc * 4 + 2][ci] = v.z;
      ls[tc * 4 + 3][ci] = v.w;
    }
    __syncthreads();
    if (tid < 64) {
#pragma unroll 4
      for (int k = 0; k < 128; ++k)
        xacc = fmaf(ls[tid][k], w1x1[half * 128 + k], xacc);
    }
#pragma unroll
    for (int s = 0; s < 4; ++s) {
      int o = tid + s * 256;               // 0..1023
      int ci8 = o & 15, t = o >> 4;
      s16x8 pk;
#pragma unroll
      for (int i = 0; i < 8; ++i) {
        __hip_bfloat16 hv = __float2bfloat16(ls[t][ci8 * 8 + i]);
        pk[i] = *(short*)&hv;
      }
      *(s16x8*)(xT + ((size_t)(b * TN) + t0 + t) * 256 + half * 128 + ci8 * 8) = pk;
    }
  }
  if (tid < 64) xx[b * TN + t0 + tid] = xacc;
}

// ========== K1: bf16 MFMA GEMM + BN + GLU ==========
__global__ __launch_bounds__(256) void k1_mfma(
    const short* __restrict__ xT, const short* __restrict__ wBpk,
    const float4* __restrict__ bnp, __hip_bfloat16* __restrict__ featT) {
  int f = blockIdx.x + 4 * (blockIdx.y + 32 * blockIdx.z);  // 0..2047
  int w = (f & 7) * 256 + (f >> 3);        // XCD-bijective: A-tile sharers on one XCD
  int nblk = w & 3, ty = (w >> 2) & 31, b = w >> 7;
  int t0 = ty * 128;
  int tid = threadIdx.x;
  int l = tid & 63, wv = tid >> 6;
  int wm = wv & 1, wn = wv >> 1;
  int tb = t0 + wm * 64;
  int nb16 = nblk * 8 + wn * 4;            // n16 base (4 frags of 16 cols)

  f32x4 acc[4][4];
#pragma unroll
  for (int i = 0; i < 4; ++i)
#pragma unroll
    for (int j = 0; j < 4; ++j) acc[i][j] = (f32x4){0.f, 0.f, 0.f, 0.f};

  const short* arow = xT + ((size_t)(b * TN) + tb + (l & 15)) * 256 + (l >> 4) * 8;
  const short* wrow = wBpk + l * 8;

#pragma unroll 2
  for (int ks = 0; ks < 8; ++ks) {
    s16x8 af[4], bf[4];
#pragma unroll
    for (int mf = 0; mf < 4; ++mf)
      af[mf] = *(const s16x8*)(arow + mf * 16 * 256 + ks * 32);
#pragma unroll
    for (int nf = 0; nf < 4; ++nf)
      bf[nf] = *(const s16x8*)(wrow + (size_t)(nb16 + nf) * 4096 + ks * 512);
#pragma unroll
    for (int mf = 0; mf < 4; ++mf)
#pragma unroll
      for (int nf = 0; nf < 4; ++nf)
        acc[mf][nf] = __builtin_amdgcn_mfma_f32_16x16x32_bf16(
            af[mf], bf[nf], acc[mf][nf], 0, 0, 0);
  }

  // epilogue: BN + GLU (packed col j pairs with j+32 -> frag nf vs nf+2, same lane)
  int cb = (nblk * 2 + wn) * 32;
#pragma unroll
  for (int nf = 0; nf < 2; ++nf) {
    float4 bn = bnp[cb + nf * 16 + (l & 15)];
    int c = cb + nf * 16 + (l & 15);
#pragma unroll
    for (int mf = 0; mf < 4; ++mf) {
#pragma unroll
      for (int r = 0; r < 4; ++r) {
        float a = acc[mf][nf][r], g = acc[mf][nf + 2][r];
        float av = fmaf(a, bn.x, bn.y);
        float gv = fmaf(g, bn.z, bn.w);
        float fv = av / (1.f + __expf(-gv));
        int t = tb + mf * 16 + (l >> 4) * 4 + r;
        featT[((size_t)b * TN + t) * 256 + c] = __float2bfloat16(fv);
      }
    }
  }
}

// ========== K2: fused predictor; p0 = VALU f32, p1/p2 = MFMA bf16 ==========
// grid (32 t-tiles of 128, 16 b), 512 thr = 8 waves.
__global__ __launch_bounds__(512) void k2_pred(
    const float* __restrict__ xx,
    const float* __restrict__ wp0T, const float2* __restrict__ bnp0,
    const short* __restrict__ wp1M, const float2* __restrict__ bnp1,
    const short* __restrict__ wp2M, const float* __restrict__ p2_b,
    const float* __restrict__ norm_mean,
    float* __restrict__ wts, float* __restrict__ mvr) {
  int t0 = blockIdx.x * 128;
  int b = blockIdx.y;
  __shared__ float xin[2][192];     // t = t0-29+q, valid q<186
  __shared__ short h0T[160 * 40];
  __shared__ short h1T[144 * 40];
  int tid = threadIdx.x;
  for (int q = tid; q < 192; q += 512) {
    int t = t0 - 29 + q;
    float v = (q < 186 && t >= 0 && t < TN) ? xx[b * TN + t] : 0.f;
    xin[0][q] = v;
    xin[1][q] = v * v;
  }
  __syncthreads();
  {  // p0: K=31, 2 in-ch, f32 VALU; thread (ch, tq) -> 12 outputs
    int ch = tid & 31, tq = tid >> 5;    // tq 0..15
    int i0 = tq * 12;
    if (i0 < 156) {
      float2 bb0 = bnp0[ch];
      float a0[12];
#pragma unroll
      for (int j = 0; j < 12; ++j) a0[j] = 0.f;
#pragma unroll
      for (int ic = 0; ic < 2; ++ic) {
        float rr[44];
#pragma unroll
        for (int q = 0; q < 11; ++q) {
          float4 t4 = *(const float4*)(&xin[ic][i0 + q * 4]);
          rr[q * 4 + 0] = t4.x; rr[q * 4 + 1] = t4.y;
          rr[q * 4 + 2] = t4.z; rr[q * 4 + 3] = t4.w;
        }
#pragma unroll
        for (int k = 0; k < 31; ++k) {
          float w = wp0T[(ic * 31 + k) * 32 + ch];
#pragma unroll
          for (int j = 0; j < 12; ++j) a0[j] = fmaf(w, rr[j + k], a0[j]);
        }
      }
#pragma unroll
      for (int j = 0; j < 12; ++j) {
        int i = i0 + j;
        if (i < 156) {
          float v = a0[j] * bb0.x + bb0.y;
          float h = v / (1.f + __expf(-v));
          __hip_bfloat16 hv = __float2bfloat16(h);
          h0T[i * 40 + ch] = *(short*)&hv;
        }
      }
    }
    if (tid < 128) h0T[(156 + (tid >> 5)) * 40 + (tid & 31)] = 0;  // zero pad rows
  }
  __syncthreads();
  int l = tid & 63, wv = tid >> 6;
  int lrow = l & 15, lk8 = (l >> 4) * 8;
  {  // p1: 15 shifted MFMAs (K=32=ic); 9 m-frags over 8 waves (wave0 gets 2)
    f32x4 acc[2][2];
#pragma unroll
    for (int i = 0; i < 2; ++i)
#pragma unroll
      for (int j = 0; j < 2; ++j) acc[i][j] = (f32x4){0.f, 0.f, 0.f, 0.f};
    int nmf = (wv == 0) ? 2 : 1;
    for (int koff = 0; koff < 15; ++koff) {
      const short* bp = wp1M + koff * 1024;
      s16x8 bf0 = *(const s16x8*)(bp + l * 8);
      s16x8 bf1 = *(const s16x8*)(bp + 512 + l * 8);
      for (int mi = 0; mi < nmf; ++mi) {
        int mf = (mi == 0) ? wv : 8;
        s16x8 af = *(const s16x8*)(&h0T[(mf * 16 + koff + lrow) * 40 + lk8]);
        acc[mi][0] = __builtin_amdgcn_mfma_f32_16x16x32_bf16(af, bf0, acc[mi][0], 0, 0, 0);
        acc[mi][1] = __builtin_amdgcn_mfma_f32_16x16x32_bf16(af, bf1, acc[mi][1], 0, 0, 0);
      }
    }
    for (int mi = 0; mi < nmf; ++mi) {
      int mf = (mi == 0) ? wv : 8;
#pragma unroll
      for (int nf = 0; nf < 2; ++nf) {
        int ch = nf * 16 + lrow;
        float2 bb = bnp1[ch];
#pragma unroll
        for (int r = 0; r < 4; ++r) {
          int row = mf * 16 + (l >> 4) * 4 + r;
          float v = acc[mi][nf][r] * bb.x + bb.y;
          float h = v / (1.f + __expf(-v));
          __hip_bfloat16 hv = __float2bfloat16(h);
          h1T[row * 40 + ch] = *(short*)&hv;
        }
      }
    }
  }
  __syncthreads();
  {  // p2: 15 shifted MFMAs, N=16 (2 cols used); 8 m-frags = 1/wave
    f32x4 acc2 = (f32x4){0.f, 0.f, 0.f, 0.f};
    for (int koff = 0; koff < 15; ++koff) {
      s16x8 bf = *(const s16x8*)(wp2M + koff * 512 + l * 8);
      s16x8 af = *(const s16x8*)(&h1T[(wv * 16 + koff + lrow) * 40 + lk8]);
      acc2 = __builtin_amdgcn_mfma_f32_16x16x32_bf16(af, bf, acc2, 0, 0, 0);
    }
    int ch = lrow;
    if (ch < 2) {
      float pb = p2_b[ch];
      float nm = norm_mean[0];
#pragma unroll
      for (int r = 0; r < 4; ++r) {
        int t = t0 + wv * 16 + (l >> 4) * 4 + r;
        float a = acc2[r] + pb;
        float s = 1.f / (1.f + __expf(-a));
        if (ch == 0) wts[b * TN + t] = s;
        else         mvr[b * TN + t] = s * nm;
      }
    }
  }
}

// ========== K3: per-batch renorm + cumsum + first_t ==========
__global__ __launch_bounds__(256) void k3_scan(const float* __restrict__ mvr,
                                               float* __restrict__ poses,
                                               int* __restrict__ firstT) {
  int b = blockIdx.x, tid = threadIdx.x;
  __shared__ float csum[256];
  __shared__ int shlast;
  float v[16];
  const float* src = mvr + b * TN + tid * 16;
  float run = 0.f;
#pragma unroll
  for (int j = 0; j < 16; ++j) { run += src[j]; v[j] = run; }
  csum[tid] = run;
  __syncthreads();
  for (int off = 1; off < 256; off <<= 1) {
    float tv = (tid >= off) ? csum[tid - off] : 0.f;
    __syncthreads();
    csum[tid] += tv;
    __syncthreads();
  }
  float incl = csum[tid];
  float total = csum[255];
  float excl = incl - run;
  __syncthreads();
  float rn = total * (1.0f / 4096.0f);
  float inv = (rn > 1.0f) ? 1.0f / rn : 1.0f;
  float p16[16];
  float* pd = poses + b * TN + tid * 16;
#pragma unroll
  for (int j = 0; j < 16; ++j) { p16[j] = (excl + v[j]) * inv; pd[j] = p16[j]; }
  csum[tid] = p16[15];
  __syncthreads();
  int* ft = firstT + b * FTS;
  int prevf = (tid == 0) ? -1 : min((int)floorf(csum[tid - 1]), 4220);
  int f = prevf;
#pragma unroll
  for (int j = 0; j < 16; ++j) {
    f = min((int)floorf(p16[j]), 4220);
    for (int l = prevf + 1; l <= f; ++l) ft[l] = tid * 16 + j;
    prevf = f;
  }
  if (tid == 255) shlast = f;
  __syncthreads();
  for (int l = shlast + 1 + tid; l < FTS; l += 256) ft[l] = TN;
}

// ========== K4: gather pool v3 — register running-sums, 16-row tiles ==========
// grid (257, 16) -> 4112 blocks, XCD-chunked swizzle (4112 = 8*514). 256 thr.
// fi monotone & wave-uniform: S_lo(row cur) / S_hi(row cur+1) in registers;
// one LDS store per row-advance (store-once, no RMW); R4-style coalesced dump.
__global__ __launch_bounds__(256) void k4_gather(
    const __hip_bfloat16* __restrict__ featT, const float* __restrict__ wts,
    const float* __restrict__ poses, const int* __restrict__ firstT,
    float* __restrict__ out) {
  int d = blockIdx.x + 257 * blockIdx.y;         // 0..4111
  int w = (d & 7) * 514 + (d >> 3);              // XCD k owns b in [2k,2k+2), all lx
  int lx = w % 257, b = w / 257;
  int l0 = lx * 16;
  __shared__ float acc[16][259];
  int tid = threadIdx.x;
  for (int i = tid; i < 16 * 259; i += 256) ((float*)acc)[i] = 0.f;
  const int* ft = firstT + b * FTS;
  int ts = (l0 == 0) ? 0 : ft[l0 - 1];
  int te = ft[l0 + 16];
  __syncthreads();
  int c = tid;
  if (ts < te) {
    const float* pp = poses + b * TN;
    const float* wp = wts + b * TN;
    const __hip_bfloat16* fp = featT + (size_t)(b * TN) * 256 + c;
    float p_cur = pp[ts];
    float w_cur = wp[ts];
    float f_cur = __bfloat162float(fp[(size_t)ts * 256]);
    float S_lo = 0.f, S_hi = 0.f;
    int cur = (int)floorf(p_cur);
    for (int t = ts; t < te; ++t) {
      float p_nxt = 0.f, w_nxt = 0.f, f_nxt = 0.f;
      if (t + 1 < te) {                          // prefetch next iter
        p_nxt = pp[t + 1];
        w_nxt = wp[t + 1];
        f_nxt = __bfloat162float(fp[(size_t)(t + 1) * 256]);
      }
      int fi = (int)floorf(p_cur);
      if (fi < cur) fi = cur;                    // FP scan-boundary wobble guard
      if (fi != cur) {                           // wave-uniform advance
        int r = cur - l0;
        if (r >= 0 && r < 16) acc[r][c] = S_lo;  // row cur is final
        if (fi == cur + 1) {
          S_lo = S_hi;
        } else {                                 // jump (FP anomaly / init only)
          int r2 = cur + 1 - l0;
          if (r2 >= 0 && r2 < 16) acc[r2][c] = S_hi;
          S_lo = 0.f;
        }
        S_hi = 0.f;
        cur = fi;
      }
      float w2 = p_cur - (float)fi;
      float fw = f_cur * w_cur;
      S_lo = fmaf(1.f - w2, fw, S_lo);
      S_hi = fmaf(w2, fw, S_hi);
      p_cur = p_nxt; w_cur = w_nxt; f_cur = f_nxt;
    }
    int r = cur - l0;                            // final rows
    if (r >= 0 && r < 16) acc[r][c] = S_lo;
    int r2 = cur + 1 - l0;
    if (r2 >= 0 && r2 < 16) acc[r2][c] = S_hi;
  }
  __syncthreads();
  // dump: 16 consecutive lanes cover 16 l of one c-row -> coalesced 64B segments
  for (int i = tid; i < 4096; i += 256) {
    int c2 = i >> 4, r = i & 15;
    int l = l0 + r;
    if (l < LOUT) out[((size_t)b * 256 + c2) * LOUT + l] = acc[r][c2];
  }
}

// ======================= launch =======================
extern "C" void kernel_launch(void* const* d_in, const int* in_sizes, int n_in,
                              void* d_out, int out_size, void* d_ws, size_t ws_size,
                              hipStream_t stream) {
  const float* x       = (const float*)d_in[0];
  const float* conv1_w = (const float*)d_in[1];
  const float* bn1_g   = (const float*)d_in[2];
  const float* bn1_b   = (const float*)d_in[3];
  const float* bn1_m   = (const float*)d_in[4];
  const float* bn1_v   = (const float*)d_in[5];
  const float* w1x1    = (const float*)d_in[6];
  const float* p0_w    = (const float*)d_in[7];
  const float* p0_b    = (const float*)d_in[8];
  const float* p0g     = (const float*)d_in[9];
  const float* p0bb    = (const float*)d_in[10];
  const float* p0m     = (const float*)d_in[11];
  const float* p0v     = (const float*)d_in[12];
  const float* p1_w    = (const float*)d_in[13];
  const float* p1_b    = (const float*)d_in[14];
  const float* p1g     = (const float*)d_in[15];
  const float* p1bb    = (const float*)d_in[16];
  const float* p1m     = (const float*)d_in[17];
  const float* p1v     = (const float*)d_in[18];
  const float* p2_w    = (const float*)d_in[19];
  const float* p2_b    = (const float*)d_in[20];
  const float* nmean   = (const float*)d_in[21];

  char* ws = (char*)d_ws;
  __hip_bfloat16* featT = (__hip_bfloat16*)ws;
  short* wBpk   = (short*)(ws + 33554432);
  float4* bnp   = (float4*)(ws + 33816576);
  float* wp0T   = (float*)(ws + 33820672);
  short* wp1M   = (short*)(ws + 33828864);
  short* wp2M   = (short*)(ws + 33859584);
  float2* bnp0  = (float2*)(ws + 33874944);
  float2* bnp1  = (float2*)(ws + 33875200);
  float* xx     = (float*)(ws + 33890304);
  float* wts    = (float*)(ws + 34152448);
  float* mvr    = (float*)(ws + 34414592);
  float* poses  = (float*)(ws + 34676736);
  int*   firstT = (int*)  (ws + 34938880);
  float* out    = (float*)d_out;
  short* xT     = (short*)d_out;   // scratch; K4 rewrites every element of d_out

  k0_prep<<<dim3(572), dim3(256), 0, stream>>>(
      conv1_w, p0_w, p1_w, p2_w, bn1_g, bn1_b, bn1_m, bn1_v,
      p0_b, p0g, p0bb, p0m, p0v, p1_b, p1g, p1bb, p1m, p1v,
      wBpk, bnp, wp0T, wp1M, wp2M, bnp0, bnp1);
  k0b_tr<<<dim3(64, 16), dim3(256), 0, stream>>>(x, w1x1, xT, xx);
  k1_mfma<<<dim3(4, 32, 16), dim3(256), 0, stream>>>(xT, wBpk, bnp, featT);
  k2_pred<<<dim3(32, 16), dim3(512), 0, stream>>>(xx, wp0T, bnp0, wp1M, bnp1,
                                                  wp2M, p2_b, nmean, wts, mvr);
  k3_scan<<<dim3(16), dim3(256), 0, stream>>>(mvr, poses, firstT);
  k4_gather<<<dim3(257, 16), dim3(256), 0, stream>>>(featT, wts, poses, firstT, out);
}

// Round 7
// 105.929 us; speedup vs baseline: 1.6805x; 1.1616x over previous
//
#include <hip/hip_runtime.h>
#include <hip/hip_bf16.h>

#define BB   16
#define CIN  256
#define TN   4096
#define LOUT 4110
#define FTS  4224   // first_t per-batch stride (ints)

typedef __attribute__((ext_vector_type(8))) short s16x8;
typedef __attribute__((ext_vector_type(4))) float f32x4;

// ---------------- workspace layout (bytes) ----------------
// featT  bf16 [B][T][256]        0          (33554432)
// wBpk   bf16 fragment-packed    33554432   (262144)  -> 33816576
// bnp    float4[256]             33816576   (4096)    -> 33820672
// wp0T   f32  [62][32]           33820672   (8192)    -> 33828864
// wp1M   bf16 frag-packed p1     33828864   (30720)   -> 33859584
// wp2M   bf16 frag-packed p2     33859584   (15360)   -> 33874944
// bnp0   float2[32]              33874944   (256)     -> 33875200
// bnp1   float2[32]              33875200   (256)     -> 33875456
// xx     f32  [B][T]             33890304
// wts    f32  [B][T]             34152448
// mvr    f32  [B][T]             34414592
// poses  f32  [B][T]             34676736
// firstT int  [B][4224]          34938880   (end 35209216)
// xT bf16 [B][T][256] lives in d_out (33.5MB < 67.3MB; K4 rewrites all of d_out)

// ======================= K0: weight prep =======================
__global__ __launch_bounds__(256) void k0_prep(
    const float* __restrict__ conv1_w, const float* __restrict__ p0_w,
    const float* __restrict__ p1_w, const float* __restrict__ p2_w,
    const float* __restrict__ bn1_g, const float* __restrict__ bn1_b,
    const float* __restrict__ bn1_m, const float* __restrict__ bn1_v,
    const float* __restrict__ p0_b, const float* __restrict__ p0g,
    const float* __restrict__ p0bb, const float* __restrict__ p0m,
    const float* __restrict__ p0v,
    const float* __restrict__ p1_b, const float* __restrict__ p1g,
    const float* __restrict__ p1bb, const float* __restrict__ p1m,
    const float* __restrict__ p1v,
    short* __restrict__ wBpk, float4* __restrict__ bnp,
    float* __restrict__ wp0T, short* __restrict__ wp1M,
    short* __restrict__ wp2M, float2* __restrict__ bnp0,
    float2* __restrict__ bnp1) {
  int bid = blockIdx.x, tid = threadIdx.x;
  if (bid < 512) {
    // wBpk flat: ((n16*8 + ks)*64 + l)*8 + i ; value = Wpacked[n16*16+(l&15)][ks*32+(l>>4)*8+i]
    int e = bid * 256 + tid;               // 0..131071
    int i = e & 7, l = (e >> 3) & 63, ks = (e >> 9) & 7, n16 = e >> 12;
    int n = n16 * 16 + (l & 15);           // packed col 0..511
    int j = n & 63;
    int co = (j < 32) ? ((n >> 6) * 32 + j) : (256 + (n >> 6) * 32 + (j - 32));
    int ci = ks * 32 + (l >> 4) * 8 + i;
    __hip_bfloat16 hv = __float2bfloat16(conv1_w[co * 256 + ci]);
    wBpk[e] = *(short*)&hv;
  } else {
    int idx = (bid - 512) * 256 + tid;     // 0..15359
    if (idx < 1984) {
      int ch = idx & 31, rem = idx >> 5;
      int ic = rem / 31, k = rem % 31;
      wp0T[idx] = p0_w[(ch * 2 + ic) * 31 + k];
    }
    {  // wp1M: idx bits [0:3)=i, [3:9)=l, [9)=nf, [10:..)=koff
      int i = idx & 7, l = (idx >> 3) & 63, nf = (idx >> 9) & 1, koff = idx >> 10;
      int ch = nf * 16 + (l & 15), ic = (l >> 4) * 8 + i;
      __hip_bfloat16 hv = __float2bfloat16(p1_w[(ch * 32 + ic) * 15 + koff]);
      wp1M[idx] = *(short*)&hv;
    }
    if (idx < 7680) {  // wp2M: bits [0:3)=i, [3:9)=l, [9:..)=koff
      int i = idx & 7, l = (idx >> 3) & 63, koff = idx >> 9;
      int n = l & 15, ic = (l >> 4) * 8 + i;
      float v = (n < 2) ? p2_w[(n * 32 + ic) * 15 + koff] : 0.f;
      __hip_bfloat16 hv = __float2bfloat16(v);
      wp2M[idx] = *(short*)&hv;
    }
    if (idx < 32) {
      int ch = idx;
      float sc = p0g[ch] * rsqrtf(p0v[ch] + 1e-5f);
      bnp0[ch] = make_float2(sc, (p0_b[ch] - p0m[ch]) * sc + p0bb[ch]);
    }
    if (idx >= 32 && idx < 64) {
      int ch = idx - 32;
      float sc = p1g[ch] * rsqrtf(p1v[ch] + 1e-5f);
      bnp1[ch] = make_float2(sc, (p1_b[ch] - p1m[ch]) * sc + p1bb[ch]);
    }
    if (idx < 256) {
      int c = idx;
      float sa = bn1_g[c] * rsqrtf(bn1_v[c] + 1e-3f);
      float ba = bn1_b[c] - bn1_m[c] * sa;
      float sg = bn1_g[c + 256] * rsqrtf(bn1_v[c + 256] + 1e-3f);
      float bg = bn1_b[c + 256] - bn1_m[c + 256] * sg;
      bnp[c] = make_float4(sa, ba, sg, bg);
    }
  }
}

// ============ K0b: transpose+cvt x -> xT bf16 [t][ci], + xx (f32 exact) ============
__global__ __launch_bounds__(256) void k0b_tr(
    const float* __restrict__ x, const float* __restrict__ w1x1,
    short* __restrict__ xT, float* __restrict__ xx) {
  int t0 = blockIdx.x * 64;
  int b = blockIdx.y;
  __shared__ float ls[64][129];
  int tid = threadIdx.x;
  const float* xb = x + (size_t)b * (CIN * TN);
  float xacc = 0.f;
  for (int half = 0; half < 2; ++half) {
    if (half) __syncthreads();
#pragma unroll
    for (int s = 0; s < 8; ++s) {
      int idx = tid + s * 256;             // 0..2047
      int ci = idx >> 4, tc = idx & 15;
      float4 v = *(const float4*)(xb + (size_t)(half * 128 + ci) * TN + t0 + tc * 4);
      ls[tc * 4 + 0][ci] = v.x;
      ls[tc * 4 + 1][ci] = v.y;
      ls[tc * 4 + 2][ci] = v.z;
      ls[tc * 4 + 3][ci] = v.w;
    }
    __syncthreads();
    if (tid < 64) {
#pragma unroll 4
      for (int k = 0; k < 128; ++k)
        xacc = fmaf(ls[tid][k], w1x1[half * 128 + k], xacc);
    }
#pragma unroll
    for (int s = 0; s < 4; ++s) {
      int o = tid + s * 256;               // 0..1023
      int ci8 = o & 15, t = o >> 4;
      s16x8 pk;
#pragma unroll
      for (int i = 0; i < 8; ++i) {
        __hip_bfloat16 hv = __float2bfloat16(ls[t][ci8 * 8 + i]);
        pk[i] = *(short*)&hv;
      }
      *(s16x8*)(xT + ((size_t)(b * TN) + t0 + t) * 256 + half * 128 + ci8 * 8) = pk;
    }
  }
  if (tid < 64) xx[b * TN + t0 + tid] = xacc;
}

// ========== K1 v2: LDS-staged bf16 MFMA GEMM + BN + GLU ==========
// grid (64 t-tiles of 64, 16 b), 512 thr = 8 waves. Per block: 64t x 512n x 256k.
// A-tile (64x256 bf16 = 32KB, contiguous in xT) staged ONCE via global_load_lds
// (linear LDS dest + inverse-XOR-swizzled global source; ds_read applies same XOR
// -> 2-way conflict = free). Wave wv owns GLU 64-col block wv (n16 [wv*4,wv*4+4)).
__global__ __launch_bounds__(512) void k1_mfma(
    const short* __restrict__ xT, const short* __restrict__ wBpk,
    const float4* __restrict__ bnp, __hip_bfloat16* __restrict__ featT) {
  int ty = blockIdx.x, b = blockIdx.y;
  int t0 = ty * 64;
  __shared__ __align__(16) short As[64 * 256];   // 32 KB, row = 512B = 32 slots x 16B
  int tid = threadIdx.x;
  int l = tid & 63, wv = tid >> 6;               // wv 0..7
  const short* xb = xT + ((size_t)b * TN + t0) * 256;

  // stage: 4 iters x 8 waves x (64 lanes x 16B) = 32KB; dest linear per wave
#pragma unroll
  for (int it = 0; it < 4; ++it) {
    int r = it * 16 + wv * 2 + (l >> 5);         // row 0..63
    int gs = (l & 31) ^ (r & 7);                 // inverse-swizzled source slot
    const short* gp = xb + r * 256 + gs * 8;
    __builtin_amdgcn_global_load_lds(
        (const __attribute__((address_space(1))) void*)gp,
        (__attribute__((address_space(3))) void*)(As + (it * 16 + wv * 2) * 256),
        16, 0, 0);
  }
  __syncthreads();

  f32x4 acc[4][4];
#pragma unroll
  for (int i = 0; i < 4; ++i)
#pragma unroll
    for (int j = 0; j < 4; ++j) acc[i][j] = (f32x4){0.f, 0.f, 0.f, 0.f};

  int lr = l & 15, lk = l >> 4;                  // row-in-frag, k-group
  const short* wrow = wBpk + (size_t)l * 8;

#pragma unroll 2
  for (int ks = 0; ks < 8; ++ks) {
    s16x8 bf[4], af[4];
#pragma unroll
    for (int nf = 0; nf < 4; ++nf)
      bf[nf] = *(const s16x8*)(wrow + (size_t)(wv * 4 + nf) * 4096 + ks * 512);
#pragma unroll
    for (int mf = 0; mf < 4; ++mf) {
      int r = mf * 16 + lr;
      int phys = (ks * 4 + lk) ^ (r & 7);        // swizzled 16B slot
      af[mf] = *(const s16x8*)(As + r * 256 + phys * 8);
    }
#pragma unroll
    for (int mf = 0; mf < 4; ++mf)
#pragma unroll
      for (int nf = 0; nf < 4; ++nf)
        acc[mf][nf] = __builtin_amdgcn_mfma_f32_16x16x32_bf16(
            af[mf], bf[nf], acc[mf][nf], 0, 0, 0);
  }

  // epilogue: BN + GLU (packed col j pairs with j+32 -> frag nf vs nf+2, same lane)
  int cb = wv * 32;
#pragma unroll
  for (int nf = 0; nf < 2; ++nf) {
    float4 bn = bnp[cb + nf * 16 + lr];
    int c = cb + nf * 16 + lr;
#pragma unroll
    for (int mf = 0; mf < 4; ++mf) {
#pragma unroll
      for (int r = 0; r < 4; ++r) {
        float a = acc[mf][nf][r], g = acc[mf][nf + 2][r];
        float av = fmaf(a, bn.x, bn.y);
        float gv = fmaf(g, bn.z, bn.w);
        float fv = av / (1.f + __expf(-gv));
        int t = t0 + mf * 16 + lk * 4 + r;
        featT[((size_t)b * TN + t) * 256 + c] = __float2bfloat16(fv);
      }
    }
  }
}

// ========== K2: fused predictor; p0 = VALU f32, p1/p2 = MFMA bf16 ==========
// grid (32 t-tiles of 128, 16 b), 512 thr = 8 waves.
__global__ __launch_bounds__(512) void k2_pred(
    const float* __restrict__ xx,
    const float* __restrict__ wp0T, const float2* __restrict__ bnp0,
    const short* __restrict__ wp1M, const float2* __restrict__ bnp1,
    const short* __restrict__ wp2M, const float* __restrict__ p2_b,
    const float* __restrict__ norm_mean,
    float* __restrict__ wts, float* __restrict__ mvr) {
  int t0 = blockIdx.x * 128;
  int b = blockIdx.y;
  __shared__ float xin[2][192];     // t = t0-29+q, valid q<186
  __shared__ short h0T[160 * 40];
  __shared__ short h1T[144 * 40];
  int tid = threadIdx.x;
  for (int q = tid; q < 192; q += 512) {
    int t = t0 - 29 + q;
    float v = (q < 186 && t >= 0 && t < TN) ? xx[b * TN + t] : 0.f;
    xin[0][q] = v;
    xin[1][q] = v * v;
  }
  __syncthreads();
  {  // p0: K=31, 2 in-ch, f32 VALU; thread (ch, tq) -> 12 outputs
    int ch = tid & 31, tq = tid >> 5;    // tq 0..15
    int i0 = tq * 12;
    if (i0 < 156) {
      float2 bb0 = bnp0[ch];
      float a0[12];
#pragma unroll
      for (int j = 0; j < 12; ++j) a0[j] = 0.f;
#pragma unroll
      for (int ic = 0; ic < 2; ++ic) {
        float rr[44];
#pragma unroll
        for (int q = 0; q < 11; ++q) {
          float4 t4 = *(const float4*)(&xin[ic][i0 + q * 4]);
          rr[q * 4 + 0] = t4.x; rr[q * 4 + 1] = t4.y;
          rr[q * 4 + 2] = t4.z; rr[q * 4 + 3] = t4.w;
        }
#pragma unroll
        for (int k = 0; k < 31; ++k) {
          float w = wp0T[(ic * 31 + k) * 32 + ch];
#pragma unroll
          for (int j = 0; j < 12; ++j) a0[j] = fmaf(w, rr[j + k], a0[j]);
        }
      }
#pragma unroll
      for (int j = 0; j < 12; ++j) {
        int i = i0 + j;
        if (i < 156) {
          float v = a0[j] * bb0.x + bb0.y;
          float h = v / (1.f + __expf(-v));
          __hip_bfloat16 hv = __float2bfloat16(h);
          h0T[i * 40 + ch] = *(short*)&hv;
        }
      }
    }
    if (tid < 128) h0T[(156 + (tid >> 5)) * 40 + (tid & 31)] = 0;  // zero pad rows
  }
  __syncthreads();
  int l = tid & 63, wv = tid >> 6;
  int lrow = l & 15, lk8 = (l >> 4) * 8;
  {  // p1: 15 shifted MFMAs (K=32=ic); 9 m-frags over 8 waves (wave0 gets 2)
    f32x4 acc[2][2];
#pragma unroll
    for (int i = 0; i < 2; ++i)
#pragma unroll
      for (int j = 0; j < 2; ++j) acc[i][j] = (f32x4){0.f, 0.f, 0.f, 0.f};
    int nmf = (wv == 0) ? 2 : 1;
    for (int koff = 0; koff < 15; ++koff) {
      const short* bp = wp1M + koff * 1024;
      s16x8 bf0 = *(const s16x8*)(bp + l * 8);
      s16x8 bf1 = *(const s16x8*)(bp + 512 + l * 8);
      for (int mi = 0; mi < nmf; ++mi) {
        int mf = (mi == 0) ? wv : 8;
        s16x8 af = *(const s16x8*)(&h0T[(mf * 16 + koff + lrow) * 40 + lk8]);
        acc[mi][0] = __builtin_amdgcn_mfma_f32_16x16x32_bf16(af, bf0, acc[mi][0], 0, 0, 0);
        acc[mi][1] = __builtin_amdgcn_mfma_f32_16x16x32_bf16(af, bf1, acc[mi][1], 0, 0, 0);
      }
    }
    for (int mi = 0; mi < nmf; ++mi) {
      int mf = (mi == 0) ? wv : 8;
#pragma unroll
      for (int nf = 0; nf < 2; ++nf) {
        int ch = nf * 16 + lrow;
        float2 bb = bnp1[ch];
#pragma unroll
        for (int r = 0; r < 4; ++r) {
          int row = mf * 16 + (l >> 4) * 4 + r;
          float v = acc[mi][nf][r] * bb.x + bb.y;
          float h = v / (1.f + __expf(-v));
          __hip_bfloat16 hv = __float2bfloat16(h);
          h1T[row * 40 + ch] = *(short*)&hv;
        }
      }
    }
  }
  __syncthreads();
  {  // p2: 15 shifted MFMAs, N=16 (2 cols used); 8 m-frags = 1/wave
    f32x4 acc2 = (f32x4){0.f, 0.f, 0.f, 0.f};
    for (int koff = 0; koff < 15; ++koff) {
      s16x8 bf = *(const s16x8*)(wp2M + koff * 512 + l * 8);
      s16x8 af = *(const s16x8*)(&h1T[(wv * 16 + koff + lrow) * 40 + lk8]);
      acc2 = __builtin_amdgcn_mfma_f32_16x16x32_bf16(af, bf, acc2, 0, 0, 0);
    }
    int ch = lrow;
    if (ch < 2) {
      float pb = p2_b[ch];
      float nm = norm_mean[0];
#pragma unroll
      for (int r = 0; r < 4; ++r) {
        int t = t0 + wv * 16 + (l >> 4) * 4 + r;
        float a = acc2[r] + pb;
        float s = 1.f / (1.f + __expf(-a));
        if (ch == 0) wts[b * TN + t] = s;
        else         mvr[b * TN + t] = s * nm;
      }
    }
  }
}

// ========== K3: per-batch renorm + cumsum + first_t ==========
__global__ __launch_bounds__(256) void k3_scan(const float* __restrict__ mvr,
                                               float* __restrict__ poses,
                                               int* __restrict__ firstT) {
  int b = blockIdx.x, tid = threadIdx.x;
  __shared__ float csum[256];
  __shared__ int shlast;
  float v[16];
  const float* src = mvr + b * TN + tid * 16;
  float run = 0.f;
#pragma unroll
  for (int j = 0; j < 16; ++j) { run += src[j]; v[j] = run; }
  csum[tid] = run;
  __syncthreads();
  for (int off = 1; off < 256; off <<= 1) {
    float tv = (tid >= off) ? csum[tid - off] : 0.f;
    __syncthreads();
    csum[tid] += tv;
    __syncthreads();
  }
  float incl = csum[tid];
  float total = csum[255];
  float excl = incl - run;
  __syncthreads();
  float rn = total * (1.0f / 4096.0f);
  float inv = (rn > 1.0f) ? 1.0f / rn : 1.0f;
  float p16[16];
  float* pd = poses + b * TN + tid * 16;
#pragma unroll
  for (int j = 0; j < 16; ++j) { p16[j] = (excl + v[j]) * inv; pd[j] = p16[j]; }
  csum[tid] = p16[15];
  __syncthreads();
  int* ft = firstT + b * FTS;
  int prevf = (tid == 0) ? -1 : min((int)floorf(csum[tid - 1]), 4220);
  int f = prevf;
#pragma unroll
  for (int j = 0; j < 16; ++j) {
    f = min((int)floorf(p16[j]), 4220);
    for (int l = prevf + 1; l <= f; ++l) ft[l] = tid * 16 + j;
    prevf = f;
  }
  if (tid == 255) shlast = f;
  __syncthreads();
  for (int l = shlast + 1 + tid; l < FTS; l += 256) ft[l] = TN;
}

// ========== K4: gather pool v3 — register running-sums, 16-row tiles ==========
__global__ __launch_bounds__(256) void k4_gather(
    const __hip_bfloat16* __restrict__ featT, const float* __restrict__ wts,
    const float* __restrict__ poses, const int* __restrict__ firstT,
    float* __restrict__ out) {
  int d = blockIdx.x + 257 * blockIdx.y;         // 0..4111
  int w = (d & 7) * 514 + (d >> 3);              // XCD k owns b in [2k,2k+2), all lx
  int lx = w % 257, b = w / 257;
  int l0 = lx * 16;
  __shared__ float acc[16][259];
  int tid = threadIdx.x;
  for (int i = tid; i < 16 * 259; i += 256) ((float*)acc)[i] = 0.f;
  const int* ft = firstT + b * FTS;
  int ts = (l0 == 0) ? 0 : ft[l0 - 1];
  int te = ft[l0 + 16];
  __syncthreads();
  int c = tid;
  if (ts < te) {
    const float* pp = poses + b * TN;
    const float* wp = wts + b * TN;
    const __hip_bfloat16* fp = featT + (size_t)(b * TN) * 256 + c;
    float p_cur = pp[ts];
    float w_cur = wp[ts];
    float f_cur = __bfloat162float(fp[(size_t)ts * 256]);
    float S_lo = 0.f, S_hi = 0.f;
    int cur = (int)floorf(p_cur);
    for (int t = ts; t < te; ++t) {
      float p_nxt = 0.f, w_nxt = 0.f, f_nxt = 0.f;
      if (t + 1 < te) {                          // prefetch next iter
        p_nxt = pp[t + 1];
        w_nxt = wp[t + 1];
        f_nxt = __bfloat162float(fp[(size_t)(t + 1) * 256]);
      }
      int fi = (int)floorf(p_cur);
      if (fi < cur) fi = cur;                    // FP scan-boundary wobble guard
      if (fi != cur) {                           // wave-uniform advance
        int r = cur - l0;
        if (r >= 0 && r < 16) acc[r][c] = S_lo;  // row cur is final
        if (fi == cur + 1) {
          S_lo = S_hi;
        } else {                                 // jump (FP anomaly / init only)
          int r2 = cur + 1 - l0;
          if (r2 >= 0 && r2 < 16) acc[r2][c] = S_hi;
          S_lo = 0.f;
        }
        S_hi = 0.f;
        cur = fi;
      }
      float w2 = p_cur - (float)fi;
      float fw = f_cur * w_cur;
      S_lo = fmaf(1.f - w2, fw, S_lo);
      S_hi = fmaf(w2, fw, S_hi);
      p_cur = p_nxt; w_cur = w_nxt; f_cur = f_nxt;
    }
    int r = cur - l0;                            // final rows
    if (r >= 0 && r < 16) acc[r][c] = S_lo;
    int r2 = cur + 1 - l0;
    if (r2 >= 0 && r2 < 16) acc[r2][c] = S_hi;
  }
  __syncthreads();
  // dump: 16 consecutive lanes cover 16 l of one c-row -> coalesced 64B segments
  for (int i = tid; i < 4096; i += 256) {
    int c2 = i >> 4, r = i & 15;
    int l = l0 + r;
    if (l < LOUT) out[((size_t)b * 256 + c2) * LOUT + l] = acc[r][c2];
  }
}

// ======================= launch =======================
extern "C" void kernel_launch(void* const* d_in, const int* in_sizes, int n_in,
                              void* d_out, int out_size, void* d_ws, size_t ws_size,
                              hipStream_t stream) {
  const float* x       = (const float*)d_in[0];
  const float* conv1_w = (const float*)d_in[1];
  const float* bn1_g   = (const float*)d_in[2];
  const float* bn1_b   = (const float*)d_in[3];
  const float* bn1_m   = (const float*)d_in[4];
  const float* bn1_v   = (const float*)d_in[5];
  const float* w1x1    = (const float*)d_in[6];
  const float* p0_w    = (const float*)d_in[7];
  const float* p0_b    = (const float*)d_in[8];
  const float* p0g     = (const float*)d_in[9];
  const float* p0bb    = (const float*)d_in[10];
  const float* p0m     = (const float*)d_in[11];
  const float* p0v     = (const float*)d_in[12];
  const float* p1_w    = (const float*)d_in[13];
  const float* p1_b    = (const float*)d_in[14];
  const float* p1g     = (const float*)d_in[15];
  const float* p1bb    = (const float*)d_in[16];
  const float* p1m     = (const float*)d_in[17];
  const float* p1v     = (const float*)d_in[18];
  const float* p2_w    = (const float*)d_in[19];
  const float* p2_b    = (const float*)d_in[20];
  const float* nmean   = (const float*)d_in[21];

  char* ws = (char*)d_ws;
  __hip_bfloat16* featT = (__hip_bfloat16*)ws;
  short* wBpk   = (short*)(ws + 33554432);
  float4* bnp   = (float4*)(ws + 33816576);
  float* wp0T   = (float*)(ws + 33820672);
  short* wp1M   = (short*)(ws + 33828864);
  short* wp2M   = (short*)(ws + 33859584);
  float2* bnp0  = (float2*)(ws + 33874944);
  float2* bnp1  = (float2*)(ws + 33875200);
  float* xx     = (float*)(ws + 33890304);
  float* wts    = (float*)(ws + 34152448);
  float* mvr    = (float*)(ws + 34414592);
  float* poses  = (float*)(ws + 34676736);
  int*   firstT = (int*)  (ws + 34938880);
  float* out    = (float*)d_out;
  short* xT     = (short*)d_out;   // scratch; K4 rewrites every element of d_out

  k0_prep<<<dim3(572), dim3(256), 0, stream>>>(
      conv1_w, p0_w, p1_w, p2_w, bn1_g, bn1_b, bn1_m, bn1_v,
      p0_b, p0g, p0bb, p0m, p0v, p1_b, p1g, p1bb, p1m, p1v,
      wBpk, bnp, wp0T, wp1M, wp2M, bnp0, bnp1);
  k0b_tr<<<dim3(64, 16), dim3(256), 0, stream>>>(x, w1x1, xT, xx);
  k1_mfma<<<dim3(64, 16), dim3(512), 0, stream>>>(xT, wBpk, bnp, featT);
  k2_pred<<<dim3(32, 16), dim3(512), 0, stream>>>(xx, wp0T, bnp0, wp1M, bnp1,
                                                  wp2M, p2_b, nmean, wts, mvr);
  k3_scan<<<dim3(16), dim3(256), 0, stream>>>(mvr, poses, firstT);
  k4_gather<<<dim3(257, 16), dim3(256), 0, stream>>>(featT, wts, poses, firstT, out);
}

// Round 8
// 98.489 us; speedup vs baseline: 1.8075x; 1.0755x over previous
//
#include <hip/hip_runtime.h>
#include <hip/hip_bf16.h>

#define BB   16
#define CIN  256
#define TN   4096
#define LOUT 4110
#define FTS  4224   // first_t per-batch stride (ints)

typedef __attribute__((ext_vector_type(8))) short s16x8;
typedef __attribute__((ext_vector_type(4))) float f32x4;

// ---------------- workspace layout (bytes) ----------------
// featT  bf16 [B][T][256]        0          (33554432)
// wBpk   bf16 fragment-packed    33554432   (262144)  -> 33816576
// bnp    float4[256]             33816576   (4096)    -> 33820672
// wp0T   f32  [62][32]           33820672   (8192)    -> 33828864
// wp1M   bf16 frag-packed p1     33828864   (30720)   -> 33859584
// wp2M   bf16 frag-packed p2     33859584   (15360)   -> 33874944
// bnp0   float2[32]              33874944   (256)     -> 33875200
// bnp1   float2[32]              33875200   (256)     -> 33875456
// xx     f32  [B][T]             33890304
// wts    f32  [B][T]             34152448
// mvr    f32  [B][T]             34414592
// poses  f32  [B][T]             34676736
// firstT int  [B][4224]          34938880   (end 35209216)

// ======================= K0: weight prep =======================
__global__ __launch_bounds__(256) void k0_prep(
    const float* __restrict__ conv1_w, const float* __restrict__ p0_w,
    const float* __restrict__ p1_w, const float* __restrict__ p2_w,
    const float* __restrict__ bn1_g, const float* __restrict__ bn1_b,
    const float* __restrict__ bn1_m, const float* __restrict__ bn1_v,
    const float* __restrict__ p0_b, const float* __restrict__ p0g,
    const float* __restrict__ p0bb, const float* __restrict__ p0m,
    const float* __restrict__ p0v,
    const float* __restrict__ p1_b, const float* __restrict__ p1g,
    const float* __restrict__ p1bb, const float* __restrict__ p1m,
    const float* __restrict__ p1v,
    short* __restrict__ wBpk, float4* __restrict__ bnp,
    float* __restrict__ wp0T, short* __restrict__ wp1M,
    short* __restrict__ wp2M, float2* __restrict__ bnp0,
    float2* __restrict__ bnp1) {
  int bid = blockIdx.x, tid = threadIdx.x;
  if (bid < 512) {
    // wBpk flat: ((n16*8 + ks)*64 + l)*8 + i ; value = Wpacked[n16*16+(l&15)][ks*32+(l>>4)*8+i]
    int e = bid * 256 + tid;               // 0..131071
    int i = e & 7, l = (e >> 3) & 63, ks = (e >> 9) & 7, n16 = e >> 12;
    int n = n16 * 16 + (l & 15);           // packed col 0..511
    int j = n & 63;
    int co = (j < 32) ? ((n >> 6) * 32 + j) : (256 + (n >> 6) * 32 + (j - 32));
    int ci = ks * 32 + (l >> 4) * 8 + i;
    __hip_bfloat16 hv = __float2bfloat16(conv1_w[co * 256 + ci]);
    wBpk[e] = *(short*)&hv;
  } else {
    int idx = (bid - 512) * 256 + tid;     // 0..15359
    if (idx < 1984) {
      int ch = idx & 31, rem = idx >> 5;
      int ic = rem / 31, k = rem % 31;
      wp0T[idx] = p0_w[(ch * 2 + ic) * 31 + k];
    }
    {  // wp1M: idx bits [0:3)=i, [3:9)=l, [9)=nf, [10:..)=koff
      int i = idx & 7, l = (idx >> 3) & 63, nf = (idx >> 9) & 1, koff = idx >> 10;
      int ch = nf * 16 + (l & 15), ic = (l >> 4) * 8 + i;
      __hip_bfloat16 hv = __float2bfloat16(p1_w[(ch * 32 + ic) * 15 + koff]);
      wp1M[idx] = *(short*)&hv;
    }
    if (idx < 7680) {  // wp2M: bits [0:3)=i, [3:9)=l, [9:..)=koff
      int i = idx & 7, l = (idx >> 3) & 63, koff = idx >> 9;
      int n = l & 15, ic = (l >> 4) * 8 + i;
      float v = (n < 2) ? p2_w[(n * 32 + ic) * 15 + koff] : 0.f;
      __hip_bfloat16 hv = __float2bfloat16(v);
      wp2M[idx] = *(short*)&hv;
    }
    if (idx < 32) {
      int ch = idx;
      float sc = p0g[ch] * rsqrtf(p0v[ch] + 1e-5f);
      bnp0[ch] = make_float2(sc, (p0_b[ch] - p0m[ch]) * sc + p0bb[ch]);
    }
    if (idx >= 32 && idx < 64) {
      int ch = idx - 32;
      float sc = p1g[ch] * rsqrtf(p1v[ch] + 1e-5f);
      bnp1[ch] = make_float2(sc, (p1_b[ch] - p1m[ch]) * sc + p1bb[ch]);
    }
    if (idx < 256) {
      int c = idx;
      float sa = bn1_g[c] * rsqrtf(bn1_v[c] + 1e-3f);
      float ba = bn1_b[c] - bn1_m[c] * sa;
      float sg = bn1_g[c + 256] * rsqrtf(bn1_v[c + 256] + 1e-3f);
      float bg = bn1_b[c + 256] - bn1_m[c + 256] * sg;
      bnp[c] = make_float4(sa, ba, sg, bg);
    }
  }
}

// ========== K1 v3: fused transpose + bf16 MFMA GEMM + BN + GLU + xx ==========
// grid (64 t-tiles of 64, 16 b), 512 thr = 8 waves. Per block: 64t x 512n x 256k.
// x f32 tile staged transposed into ls[64][257] (stride 257 == 1 mod 32: natural
// bank swizzle; all reads/writes <=2-way = free). A-fragments cvt f32->bf16 in
// regs (same rounding as old k0b path). xx computed from the same tile.
__global__ __launch_bounds__(512, 4) void k1_mfma(
    const float* __restrict__ x, const float* __restrict__ w1x1,
    const short* __restrict__ wBpk, const float4* __restrict__ bnp,
    __hip_bfloat16* __restrict__ featT, float* __restrict__ xx) {
  int ty = blockIdx.x, b = blockIdx.y;
  int t0 = ty * 64;
  __shared__ float ls[64][257];
  int tid = threadIdx.x;
  const float* xb = x + (size_t)b * (CIN * TN);
  // stage: 64t x 256ci f32 (64KB) = 4096 float4 loads, 8 per thread
#pragma unroll
  for (int s = 0; s < 8; ++s) {
    int idx = tid + s * 512;             // 0..4095
    int ci = idx >> 4, tc = idx & 15;
    float4 v = *(const float4*)(xb + (size_t)ci * TN + t0 + tc * 4);
    ls[tc * 4 + 0][ci] = v.x;
    ls[tc * 4 + 1][ci] = v.y;
    ls[tc * 4 + 2][ci] = v.z;
    ls[tc * 4 + 3][ci] = v.w;
  }
  __syncthreads();

  {  // xx: thread (t = tid>>3, kq = tid&7), stride-8 k-split + shfl reduce
    int t = tid >> 3, kq = tid & 7;
    float a = 0.f;
#pragma unroll 8
    for (int j = 0; j < 32; ++j)
      a = fmaf(ls[t][kq + j * 8], w1x1[kq + j * 8], a);
    a += __shfl_xor(a, 1);
    a += __shfl_xor(a, 2);
    a += __shfl_xor(a, 4);
    if (kq == 0) xx[b * TN + t0 + t] = a;
  }

  f32x4 acc[4][4];
#pragma unroll
  for (int i = 0; i < 4; ++i)
#pragma unroll
    for (int j = 0; j < 4; ++j) acc[i][j] = (f32x4){0.f, 0.f, 0.f, 0.f};

  int l = tid & 63, wv = tid >> 6;       // wave wv owns GLU 64-col block wv
  int lr = l & 15, lk = l >> 4;
  const short* wrow = wBpk + (size_t)l * 8;

#pragma unroll 2
  for (int ks = 0; ks < 8; ++ks) {
    s16x8 bf[4], af[4];
#pragma unroll
    for (int nf = 0; nf < 4; ++nf)
      bf[nf] = *(const s16x8*)(wrow + (size_t)(wv * 4 + nf) * 4096 + ks * 512);
#pragma unroll
    for (int mf = 0; mf < 4; ++mf) {
      const float* ap = &ls[mf * 16 + lr][ks * 32 + lk * 8];
      s16x8 t;
#pragma unroll
      for (int i = 0; i < 8; ++i) {
        __hip_bfloat16 hv = __float2bfloat16(ap[i]);
        t[i] = *(short*)&hv;
      }
      af[mf] = t;
    }
#pragma unroll
    for (int mf = 0; mf < 4; ++mf)
#pragma unroll
      for (int nf = 0; nf < 4; ++nf)
        acc[mf][nf] = __builtin_amdgcn_mfma_f32_16x16x32_bf16(
            af[mf], bf[nf], acc[mf][nf], 0, 0, 0);
  }

  // epilogue: BN + GLU (packed col j pairs with j+32 -> frag nf vs nf+2, same lane)
  int cb = wv * 32;
#pragma unroll
  for (int nf = 0; nf < 2; ++nf) {
    float4 bn = bnp[cb + nf * 16 + lr];
    int c = cb + nf * 16 + lr;
#pragma unroll
    for (int mf = 0; mf < 4; ++mf) {
#pragma unroll
      for (int r = 0; r < 4; ++r) {
        float a = acc[mf][nf][r], g = acc[mf][nf + 2][r];
        float av = fmaf(a, bn.x, bn.y);
        float gv = fmaf(g, bn.z, bn.w);
        float fv = av / (1.f + __expf(-gv));
        int t = t0 + mf * 16 + lk * 4 + r;
        featT[((size_t)b * TN + t) * 256 + c] = __float2bfloat16(fv);
      }
    }
  }
}

// ========== K2: fused predictor; p0 = VALU f32, p1/p2 = MFMA bf16 ==========
// grid (32 t-tiles of 128, 16 b), 512 thr = 8 waves.
__global__ __launch_bounds__(512) void k2_pred(
    const float* __restrict__ xx,
    const float* __restrict__ wp0T, const float2* __restrict__ bnp0,
    const short* __restrict__ wp1M, const float2* __restrict__ bnp1,
    const short* __restrict__ wp2M, const float* __restrict__ p2_b,
    const float* __restrict__ norm_mean,
    float* __restrict__ wts, float* __restrict__ mvr) {
  int t0 = blockIdx.x * 128;
  int b = blockIdx.y;
  __shared__ float xin[2][192];     // t = t0-29+q, valid q<186
  __shared__ short h0T[160 * 40];
  __shared__ short h1T[144 * 40];
  int tid = threadIdx.x;
  for (int q = tid; q < 192; q += 512) {
    int t = t0 - 29 + q;
    float v = (q < 186 && t >= 0 && t < TN) ? xx[b * TN + t] : 0.f;
    xin[0][q] = v;
    xin[1][q] = v * v;
  }
  __syncthreads();
  {  // p0: K=31, 2 in-ch, f32 VALU; thread (ch, tq) -> 12 outputs
    int ch = tid & 31, tq = tid >> 5;    // tq 0..15
    int i0 = tq * 12;
    if (i0 < 156) {
      float2 bb0 = bnp0[ch];
      float a0[12];
#pragma unroll
      for (int j = 0; j < 12; ++j) a0[j] = 0.f;
#pragma unroll
      for (int ic = 0; ic < 2; ++ic) {
        float rr[44];
#pragma unroll
        for (int q = 0; q < 11; ++q) {
          float4 t4 = *(const float4*)(&xin[ic][i0 + q * 4]);
          rr[q * 4 + 0] = t4.x; rr[q * 4 + 1] = t4.y;
          rr[q * 4 + 2] = t4.z; rr[q * 4 + 3] = t4.w;
        }
#pragma unroll
        for (int k = 0; k < 31; ++k) {
          float w = wp0T[(ic * 31 + k) * 32 + ch];
#pragma unroll
          for (int j = 0; j < 12; ++j) a0[j] = fmaf(w, rr[j + k], a0[j]);
        }
      }
#pragma unroll
      for (int j = 0; j < 12; ++j) {
        int i = i0 + j;
        if (i < 156) {
          float v = a0[j] * bb0.x + bb0.y;
          float h = v / (1.f + __expf(-v));
          __hip_bfloat16 hv = __float2bfloat16(h);
          h0T[i * 40 + ch] = *(short*)&hv;
        }
      }
    }
    if (tid < 128) h0T[(156 + (tid >> 5)) * 40 + (tid & 31)] = 0;  // zero pad rows
  }
  __syncthreads();
  int l = tid & 63, wv = tid >> 6;
  int lrow = l & 15, lk8 = (l >> 4) * 8;
  {  // p1: 15 shifted MFMAs (K=32=ic); 9 m-frags over 8 waves (wave0 gets 2)
    f32x4 acc[2][2];
#pragma unroll
    for (int i = 0; i < 2; ++i)
#pragma unroll
      for (int j = 0; j < 2; ++j) acc[i][j] = (f32x4){0.f, 0.f, 0.f, 0.f};
    int nmf = (wv == 0) ? 2 : 1;
    for (int koff = 0; koff < 15; ++koff) {
      const short* bp = wp1M + koff * 1024;
      s16x8 bf0 = *(const s16x8*)(bp + l * 8);
      s16x8 bf1 = *(const s16x8*)(bp + 512 + l * 8);
      for (int mi = 0; mi < nmf; ++mi) {
        int mf = (mi == 0) ? wv : 8;
        s16x8 af = *(const s16x8*)(&h0T[(mf * 16 + koff + lrow) * 40 + lk8]);
        acc[mi][0] = __builtin_amdgcn_mfma_f32_16x16x32_bf16(af, bf0, acc[mi][0], 0, 0, 0);
        acc[mi][1] = __builtin_amdgcn_mfma_f32_16x16x32_bf16(af, bf1, acc[mi][1], 0, 0, 0);
      }
    }
    for (int mi = 0; mi < nmf; ++mi) {
      int mf = (mi == 0) ? wv : 8;
#pragma unroll
      for (int nf = 0; nf < 2; ++nf) {
        int ch = nf * 16 + lrow;
        float2 bb = bnp1[ch];
#pragma unroll
        for (int r = 0; r < 4; ++r) {
          int row = mf * 16 + (l >> 4) * 4 + r;
          float v = acc[mi][nf][r] * bb.x + bb.y;
          float h = v / (1.f + __expf(-v));
          __hip_bfloat16 hv = __float2bfloat16(h);
          h1T[row * 40 + ch] = *(short*)&hv;
        }
      }
    }
  }
  __syncthreads();
  {  // p2: 15 shifted MFMAs, N=16 (2 cols used); 8 m-frags = 1/wave
    f32x4 acc2 = (f32x4){0.f, 0.f, 0.f, 0.f};
    for (int koff = 0; koff < 15; ++koff) {
      s16x8 bf = *(const s16x8*)(wp2M + koff * 512 + l * 8);
      s16x8 af = *(const s16x8*)(&h1T[(wv * 16 + koff + lrow) * 40 + lk8]);
      acc2 = __builtin_amdgcn_mfma_f32_16x16x32_bf16(af, bf, acc2, 0, 0, 0);
    }
    int ch = lrow;
    if (ch < 2) {
      float pb = p2_b[ch];
      float nm = norm_mean[0];
#pragma unroll
      for (int r = 0; r < 4; ++r) {
        int t = t0 + wv * 16 + (l >> 4) * 4 + r;
        float a = acc2[r] + pb;
        float s = 1.f / (1.f + __expf(-a));
        if (ch == 0) wts[b * TN + t] = s;
        else         mvr[b * TN + t] = s * nm;
      }
    }
  }
}

// ========== K3: per-batch renorm + cumsum + first_t ==========
__global__ __launch_bounds__(256) void k3_scan(const float* __restrict__ mvr,
                                               float* __restrict__ poses,
                                               int* __restrict__ firstT) {
  int b = blockIdx.x, tid = threadIdx.x;
  __shared__ float csum[256];
  __shared__ int shlast;
  float v[16];
  const float* src = mvr + b * TN + tid * 16;
  float run = 0.f;
#pragma unroll
  for (int j = 0; j < 16; ++j) { run += src[j]; v[j] = run; }
  csum[tid] = run;
  __syncthreads();
  for (int off = 1; off < 256; off <<= 1) {
    float tv = (tid >= off) ? csum[tid - off] : 0.f;
    __syncthreads();
    csum[tid] += tv;
    __syncthreads();
  }
  float incl = csum[tid];
  float total = csum[255];
  float excl = incl - run;
  __syncthreads();
  float rn = total * (1.0f / 4096.0f);
  float inv = (rn > 1.0f) ? 1.0f / rn : 1.0f;
  float p16[16];
  float* pd = poses + b * TN + tid * 16;
#pragma unroll
  for (int j = 0; j < 16; ++j) { p16[j] = (excl + v[j]) * inv; pd[j] = p16[j]; }
  csum[tid] = p16[15];
  __syncthreads();
  int* ft = firstT + b * FTS;
  int prevf = (tid == 0) ? -1 : min((int)floorf(csum[tid - 1]), 4220);
  int f = prevf;
#pragma unroll
  for (int j = 0; j < 16; ++j) {
    f = min((int)floorf(p16[j]), 4220);
    for (int l = prevf + 1; l <= f; ++l) ft[l] = tid * 16 + j;
    prevf = f;
  }
  if (tid == 255) shlast = f;
  __syncthreads();
  for (int l = shlast + 1 + tid; l < FTS; l += 256) ft[l] = TN;
}

// ========== K4: gather pool v3 — register running-sums, 16-row tiles ==========
__global__ __launch_bounds__(256) void k4_gather(
    const __hip_bfloat16* __restrict__ featT, const float* __restrict__ wts,
    const float* __restrict__ poses, const int* __restrict__ firstT,
    float* __restrict__ out) {
  int d = blockIdx.x + 257 * blockIdx.y;         // 0..4111
  int w = (d & 7) * 514 + (d >> 3);              // XCD k owns b in [2k,2k+2), all lx
  int lx = w % 257, b = w / 257;
  int l0 = lx * 16;
  __shared__ float acc[16][259];
  int tid = threadIdx.x;
  for (int i = tid; i < 16 * 259; i += 256) ((float*)acc)[i] = 0.f;
  const int* ft = firstT + b * FTS;
  int ts = (l0 == 0) ? 0 : ft[l0 - 1];
  int te = ft[l0 + 16];
  __syncthreads();
  int c = tid;
  if (ts < te) {
    const float* pp = poses + b * TN;
    const float* wp = wts + b * TN;
    const __hip_bfloat16* fp = featT + (size_t)(b * TN) * 256 + c;
    float p_cur = pp[ts];
    float w_cur = wp[ts];
    float f_cur = __bfloat162float(fp[(size_t)ts * 256]);
    float S_lo = 0.f, S_hi = 0.f;
    int cur = (int)floorf(p_cur);
    for (int t = ts; t < te; ++t) {
      float p_nxt = 0.f, w_nxt = 0.f, f_nxt = 0.f;
      if (t + 1 < te) {                          // prefetch next iter
        p_nxt = pp[t + 1];
        w_nxt = wp[t + 1];
        f_nxt = __bfloat162float(fp[(size_t)(t + 1) * 256]);
      }
      int fi = (int)floorf(p_cur);
      if (fi < cur) fi = cur;                    // FP scan-boundary wobble guard
      if (fi != cur) {                           // wave-uniform advance
        int r = cur - l0;
        if (r >= 0 && r < 16) acc[r][c] = S_lo;  // row cur is final
        if (fi == cur + 1) {
          S_lo = S_hi;
        } else {                                 // jump (FP anomaly / init only)
          int r2 = cur + 1 - l0;
          if (r2 >= 0 && r2 < 16) acc[r2][c] = S_hi;
          S_lo = 0.f;
        }
        S_hi = 0.f;
        cur = fi;
      }
      float w2 = p_cur - (float)fi;
      float fw = f_cur * w_cur;
      S_lo = fmaf(1.f - w2, fw, S_lo);
      S_hi = fmaf(w2, fw, S_hi);
      p_cur = p_nxt; w_cur = w_nxt; f_cur = f_nxt;
    }
    int r = cur - l0;                            // final rows
    if (r >= 0 && r < 16) acc[r][c] = S_lo;
    int r2 = cur + 1 - l0;
    if (r2 >= 0 && r2 < 16) acc[r2][c] = S_hi;
  }
  __syncthreads();
  // dump: 16 consecutive lanes cover 16 l of one c-row -> coalesced 64B segments
  for (int i = tid; i < 4096; i += 256) {
    int c2 = i >> 4, r = i & 15;
    int l = l0 + r;
    if (l < LOUT) out[((size_t)b * 256 + c2) * LOUT + l] = acc[r][c2];
  }
}

// ======================= launch =======================
extern "C" void kernel_launch(void* const* d_in, const int* in_sizes, int n_in,
                              void* d_out, int out_size, void* d_ws, size_t ws_size,
                              hipStream_t stream) {
  const float* x       = (const float*)d_in[0];
  const float* conv1_w = (const float*)d_in[1];
  const float* bn1_g   = (const float*)d_in[2];
  const float* bn1_b   = (const float*)d_in[3];
  const float* bn1_m   = (const float*)d_in[4];
  const float* bn1_v   = (const float*)d_in[5];
  const float* w1x1    = (const float*)d_in[6];
  const float* p0_w    = (const float*)d_in[7];
  const float* p0_b    = (const float*)d_in[8];
  const float* p0g     = (const float*)d_in[9];
  const float* p0bb    = (const float*)d_in[10];
  const float* p0m     = (const float*)d_in[11];
  const float* p0v     = (const float*)d_in[12];
  const float* p1_w    = (const float*)d_in[13];
  const float* p1_b    = (const float*)d_in[14];
  const float* p1g     = (const float*)d_in[15];
  const float* p1bb    = (const float*)d_in[16];
  const float* p1m     = (const float*)d_in[17];
  const float* p1v     = (const float*)d_in[18];
  const float* p2_w    = (const float*)d_in[19];
  const float* p2_b    = (const float*)d_in[20];
  const float* nmean   = (const float*)d_in[21];

  char* ws = (char*)d_ws;
  __hip_bfloat16* featT = (__hip_bfloat16*)ws;
  short* wBpk   = (short*)(ws + 33554432);
  float4* bnp   = (float4*)(ws + 33816576);
  float* wp0T   = (float*)(ws + 33820672);
  short* wp1M   = (short*)(ws + 33828864);
  short* wp2M   = (short*)(ws + 33859584);
  float2* bnp0  = (float2*)(ws + 33874944);
  float2* bnp1  = (float2*)(ws + 33875200);
  float* xx     = (float*)(ws + 33890304);
  float* wts    = (float*)(ws + 34152448);
  float* mvr    = (float*)(ws + 34414592);
  float* poses  = (float*)(ws + 34676736);
  int*   firstT = (int*)  (ws + 34938880);
  float* out    = (float*)d_out;

  k0_prep<<<dim3(572), dim3(256), 0, stream>>>(
      conv1_w, p0_w, p1_w, p2_w, bn1_g, bn1_b, bn1_m, bn1_v,
      p0_b, p0g, p0bb, p0m, p0v, p1_b, p1g, p1bb, p1m, p1v,
      wBpk, bnp, wp0T, wp1M, wp2M, bnp0, bnp1);
  k1_mfma<<<dim3(64, 16), dim3(512), 0, stream>>>(x, w1x1, wBpk, bnp, featT, xx);
  k2_pred<<<dim3(32, 16), dim3(512), 0, stream>>>(xx, wp0T, bnp0, wp1M, bnp1,
                                                  wp2M, p2_b, nmean, wts, mvr);
  k3_scan<<<dim3(16), dim3(256), 0, stream>>>(mvr, poses, firstT);
  k4_gather<<<dim3(257, 16), dim3(256), 0, stream>>>(featT, wts, poses, firstT, out);
}

// Round 9
// 95.591 us; speedup vs baseline: 1.8623x; 1.0303x over previous
//
#include <hip/hip_runtime.h>
#include <hip/hip_bf16.h>

#define BB   16
#define CIN  256
#define TN   4096
#define LOUT 4110
#define FTS  4224   // first_t per-batch stride (ints)

typedef __attribute__((ext_vector_type(8))) short s16x8;
typedef __attribute__((ext_vector_type(4))) float f32x4;

// ---------------- workspace layout (bytes) ----------------
// featT  bf16 [B][T][256]        0          (33554432)
// wBpk   bf16 fragment-packed    33554432   (262144)  -> 33816576
// bnp    float4[256]             33816576   (4096)    -> 33820672
// wp0T   f32  [62][32]           33820672   (8192)    -> 33828864
// wp1M   bf16 frag-packed p1     33828864   (30720)   -> 33859584
// wp2M   bf16 frag-packed p2     33859584   (15360)   -> 33874944
// bnp0   float2[32]              33874944   (256)     -> 33875200
// bnp1   float2[32]              33875200   (256)     -> 33875456
// xx     f32  [B][T]             33890304
// wts    f32  [B][T]             34152448
// mvr    f32  [B][T]             34414592
// poses  f32  [B][T]             34676736
// firstT int  [B][4224]          34938880   (end 35209216)

// ======================= K0: weight prep =======================
__global__ __launch_bounds__(256) void k0_prep(
    const float* __restrict__ conv1_w, const float* __restrict__ p0_w,
    const float* __restrict__ p1_w, const float* __restrict__ p2_w,
    const float* __restrict__ bn1_g, const float* __restrict__ bn1_b,
    const float* __restrict__ bn1_m, const float* __restrict__ bn1_v,
    const float* __restrict__ p0_b, const float* __restrict__ p0g,
    const float* __restrict__ p0bb, const float* __restrict__ p0m,
    const float* __restrict__ p0v,
    const float* __restrict__ p1_b, const float* __restrict__ p1g,
    const float* __restrict__ p1bb, const float* __restrict__ p1m,
    const float* __restrict__ p1v,
    short* __restrict__ wBpk, float4* __restrict__ bnp,
    float* __restrict__ wp0T, short* __restrict__ wp1M,
    short* __restrict__ wp2M, float2* __restrict__ bnp0,
    float2* __restrict__ bnp1) {
  int bid = blockIdx.x, tid = threadIdx.x;
  if (bid < 512) {
    // wBpk flat: ((n16*8 + ks)*64 + l)*8 + i ; value = Wpacked[n16*16+(l&15)][ks*32+(l>>4)*8+i]
    int e = bid * 256 + tid;               // 0..131071
    int i = e & 7, l = (e >> 3) & 63, ks = (e >> 9) & 7, n16 = e >> 12;
    int n = n16 * 16 + (l & 15);           // packed col 0..511
    int j = n & 63;
    int co = (j < 32) ? ((n >> 6) * 32 + j) : (256 + (n >> 6) * 32 + (j - 32));
    int ci = ks * 32 + (l >> 4) * 8 + i;
    __hip_bfloat16 hv = __float2bfloat16(conv1_w[co * 256 + ci]);
    wBpk[e] = *(short*)&hv;
  } else {
    int idx = (bid - 512) * 256 + tid;     // 0..15359
    if (idx < 1984) {
      int ch = idx & 31, rem = idx >> 5;
      int ic = rem / 31, k = rem % 31;
      wp0T[idx] = p0_w[(ch * 2 + ic) * 31 + k];
    }
    {  // wp1M: idx bits [0:3)=i, [3:9)=l, [9)=nf, [10:..)=koff
      int i = idx & 7, l = (idx >> 3) & 63, nf = (idx >> 9) & 1, koff = idx >> 10;
      int ch = nf * 16 + (l & 15), ic = (l >> 4) * 8 + i;
      __hip_bfloat16 hv = __float2bfloat16(p1_w[(ch * 32 + ic) * 15 + koff]);
      wp1M[idx] = *(short*)&hv;
    }
    if (idx < 7680) {  // wp2M: bits [0:3)=i, [3:9)=l, [9:..)=koff
      int i = idx & 7, l = (idx >> 3) & 63, koff = idx >> 9;
      int n = l & 15, ic = (l >> 4) * 8 + i;
      float v = (n < 2) ? p2_w[(n * 32 + ic) * 15 + koff] : 0.f;
      __hip_bfloat16 hv = __float2bfloat16(v);
      wp2M[idx] = *(short*)&hv;
    }
    if (idx < 32) {
      int ch = idx;
      float sc = p0g[ch] * rsqrtf(p0v[ch] + 1e-5f);
      bnp0[ch] = make_float2(sc, (p0_b[ch] - p0m[ch]) * sc + p0bb[ch]);
    }
    if (idx >= 32 && idx < 64) {
      int ch = idx - 32;
      float sc = p1g[ch] * rsqrtf(p1v[ch] + 1e-5f);
      bnp1[ch] = make_float2(sc, (p1_b[ch] - p1m[ch]) * sc + p1bb[ch]);
    }
    if (idx < 256) {
      int c = idx;
      float sa = bn1_g[c] * rsqrtf(bn1_v[c] + 1e-3f);
      float ba = bn1_b[c] - bn1_m[c] * sa;
      float sg = bn1_g[c + 256] * rsqrtf(bn1_v[c + 256] + 1e-3f);
      float bg = bn1_b[c + 256] - bn1_m[c + 256] * sg;
      bnp[c] = make_float4(sa, ba, sg, bg);
    }
  }
}

// ========== K1 v4: fused transpose->bf16-LDS + MFMA GEMM + BN + GLU + xx ==========
// grid 4096 flat: bid -> xcd = bid&7; k = bid>>3; nblk = k&3; T = (k>>2)*8 + xcd;
// (all 4 nblk sharers of one A-tile land on the same XCD for L2 reuse of x.)
// Block: 256 thr = 4 waves; tile 64t x 128n x 256k. LDS hb[64][132] u32 = bf16
// pairs (ci even, ci odd), cvt done ONCE at staging. XOR swizzle on 16B group id
// (grp ^ ((row>>3)&3)) applied on both write and read -> balanced banks.
// Wave wv owns GLU-paired frags n16a, n16a+2 -> register GLU epilogue.
__global__ __launch_bounds__(256, 4) void k1_mfma(
    const float* __restrict__ x, const float* __restrict__ w1x1,
    const short* __restrict__ wBpk, const float4* __restrict__ bnp,
    __hip_bfloat16* __restrict__ featT, float* __restrict__ xx) {
  int bid = blockIdx.x;
  int xcd = bid & 7, kk = bid >> 3;
  int nblk = kk & 3;
  int T = (kk >> 2) * 8 + xcd;           // 0..1023
  int ty = T & 63, b = T >> 6;
  int t0 = ty * 64;
  __shared__ __align__(16) unsigned int hb[64 * 132];
  __shared__ float xws[4][68];
  int tid = threadIdx.x;
  int l = tid & 63, wv = tid >> 6;
  int tq = l & 15, Cb = l >> 4;
  int q = (tq >> 1) & 3;
  const float* xb = x + (size_t)b * (CIN * TN) + t0 + 4 * tq;
  float xxp[4] = {0.f, 0.f, 0.f, 0.f};
#pragma unroll 2
  for (int iter = 0; iter < 8; ++iter) {
    int C = 4 * wv + Cb + 16 * iter;     // cpair 0..127
    int ci = 2 * C;
    float4 f0 = *(const float4*)(xb + (size_t)ci * TN);
    float4 f1 = *(const float4*)(xb + (size_t)(ci + 1) * TN);
    float w0 = w1x1[ci], w1 = w1x1[ci + 1];
    unsigned int* dst = hb + (C ^ (q << 2));
    float fa[4] = {f0.x, f0.y, f0.z, f0.w};
    float fb[4] = {f1.x, f1.y, f1.z, f1.w};
#pragma unroll
    for (int r = 0; r < 4; ++r) {
      __hip_bfloat16 lo = __float2bfloat16(fa[r]);
      __hip_bfloat16 hi = __float2bfloat16(fb[r]);
      unsigned int pk = (unsigned int)(*(unsigned short*)&lo) |
                        ((unsigned int)(*(unsigned short*)&hi) << 16);
      dst[(4 * tq + r) * 132] = pk;
      xxp[r] = fmaf(w0, fa[r], fmaf(w1, fb[r], xxp[r]));
    }
  }
#pragma unroll
  for (int r = 0; r < 4; ++r) {          // reduce over Cb (lanes stride 16)
    xxp[r] += __shfl_xor(xxp[r], 16);
    xxp[r] += __shfl_xor(xxp[r], 32);
  }
  if (Cb == 0) {
#pragma unroll
    for (int r = 0; r < 4; ++r) xws[wv][4 * tq + r] = xxp[r];
  }
  __syncthreads();
  if (tid < 64)
    xx[b * TN + t0 + tid] = xws[0][tid] + xws[1][tid] + xws[2][tid] + xws[3][tid];

  f32x4 acc[4][2];
#pragma unroll
  for (int i = 0; i < 4; ++i) {
    acc[i][0] = (f32x4){0.f, 0.f, 0.f, 0.f};
    acc[i][1] = (f32x4){0.f, 0.f, 0.f, 0.f};
  }
  int lr = l & 15, lk = l >> 4;
  int glu = 2 * nblk + (wv >> 1), sub = wv & 1;
  int n16a = glu * 4 + sub;              // partner frag = n16a + 2 (GLU pair)
  const short* wrow = wBpk + (size_t)l * 8;

#pragma unroll 2
  for (int ks = 0; ks < 8; ++ks) {
    s16x8 bf0 = *(const s16x8*)(wrow + (size_t)n16a * 4096 + ks * 512);
    s16x8 bf1 = *(const s16x8*)(wrow + (size_t)(n16a + 2) * 4096 + ks * 512);
#pragma unroll
    for (int mf = 0; mf < 4; ++mf) {
      int row = mf * 16 + lr;
      int grp = ks * 4 + lk;
      int qr = (row >> 3) & 3;
      s16x8 af = *(const s16x8*)(hb + row * 132 + ((grp ^ qr) << 2));
      acc[mf][0] = __builtin_amdgcn_mfma_f32_16x16x32_bf16(af, bf0, acc[mf][0], 0, 0, 0);
      acc[mf][1] = __builtin_amdgcn_mfma_f32_16x16x32_bf16(af, bf1, acc[mf][1], 0, 0, 0);
    }
  }

  // epilogue: BN + GLU (frag n16a col j pairs with n16a+2 col j+32, same lane)
  int c = glu * 32 + sub * 16 + lr;
  float4 bn = bnp[c];
#pragma unroll
  for (int mf = 0; mf < 4; ++mf) {
#pragma unroll
    for (int r = 0; r < 4; ++r) {
      float a = acc[mf][0][r], g = acc[mf][1][r];
      float av = fmaf(a, bn.x, bn.y);
      float gv = fmaf(g, bn.z, bn.w);
      float fv = av / (1.f + __expf(-gv));
      int t = t0 + mf * 16 + lk * 4 + r;
      featT[((size_t)b * TN + t) * 256 + c] = __float2bfloat16(fv);
    }
  }
}

// ========== K2: fused predictor; p0 = VALU f32, p1/p2 = MFMA bf16 ==========
// grid (32 t-tiles of 128, 16 b), 512 thr = 8 waves.
__global__ __launch_bounds__(512) void k2_pred(
    const float* __restrict__ xx,
    const float* __restrict__ wp0T, const float2* __restrict__ bnp0,
    const short* __restrict__ wp1M, const float2* __restrict__ bnp1,
    const short* __restrict__ wp2M, const float* __restrict__ p2_b,
    const float* __restrict__ norm_mean,
    float* __restrict__ wts, float* __restrict__ mvr) {
  int t0 = blockIdx.x * 128;
  int b = blockIdx.y;
  __shared__ float xin[2][192];     // t = t0-29+q, valid q<186
  __shared__ short h0T[160 * 40];
  __shared__ short h1T[144 * 40];
  int tid = threadIdx.x;
  for (int q = tid; q < 192; q += 512) {
    int t = t0 - 29 + q;
    float v = (q < 186 && t >= 0 && t < TN) ? xx[b * TN + t] : 0.f;
    xin[0][q] = v;
    xin[1][q] = v * v;
  }
  __syncthreads();
  {  // p0: K=31, 2 in-ch, f32 VALU; thread (ch, tq) -> 12 outputs
    int ch = tid & 31, tq = tid >> 5;    // tq 0..15
    int i0 = tq * 12;
    if (i0 < 156) {
      float2 bb0 = bnp0[ch];
      float a0[12];
#pragma unroll
      for (int j = 0; j < 12; ++j) a0[j] = 0.f;
#pragma unroll
      for (int ic = 0; ic < 2; ++ic) {
        float rr[44];
#pragma unroll
        for (int q = 0; q < 11; ++q) {
          float4 t4 = *(const float4*)(&xin[ic][i0 + q * 4]);
          rr[q * 4 + 0] = t4.x; rr[q * 4 + 1] = t4.y;
          rr[q * 4 + 2] = t4.z; rr[q * 4 + 3] = t4.w;
        }
#pragma unroll
        for (int k = 0; k < 31; ++k) {
          float w = wp0T[(ic * 31 + k) * 32 + ch];
#pragma unroll
          for (int j = 0; j < 12; ++j) a0[j] = fmaf(w, rr[j + k], a0[j]);
        }
      }
#pragma unroll
      for (int j = 0; j < 12; ++j) {
        int i = i0 + j;
        if (i < 156) {
          float v = a0[j] * bb0.x + bb0.y;
          float h = v / (1.f + __expf(-v));
          __hip_bfloat16 hv = __float2bfloat16(h);
          h0T[i * 40 + ch] = *(short*)&hv;
        }
      }
    }
    if (tid < 128) h0T[(156 + (tid >> 5)) * 40 + (tid & 31)] = 0;  // zero pad rows
  }
  __syncthreads();
  int l = tid & 63, wv = tid >> 6;
  int lrow = l & 15, lk8 = (l >> 4) * 8;
  {  // p1: 15 shifted MFMAs (K=32=ic); 9 m-frags over 8 waves (wave0 gets 2)
    f32x4 acc[2][2];
#pragma unroll
    for (int i = 0; i < 2; ++i)
#pragma unroll
      for (int j = 0; j < 2; ++j) acc[i][j] = (f32x4){0.f, 0.f, 0.f, 0.f};
    int nmf = (wv == 0) ? 2 : 1;
    for (int koff = 0; koff < 15; ++koff) {
      const short* bp = wp1M + koff * 1024;
      s16x8 bf0 = *(const s16x8*)(bp + l * 8);
      s16x8 bf1 = *(const s16x8*)(bp + 512 + l * 8);
      for (int mi = 0; mi < nmf; ++mi) {
        int mf = (mi == 0) ? wv : 8;
        s16x8 af = *(const s16x8*)(&h0T[(mf * 16 + koff + lrow) * 40 + lk8]);
        acc[mi][0] = __builtin_amdgcn_mfma_f32_16x16x32_bf16(af, bf0, acc[mi][0], 0, 0, 0);
        acc[mi][1] = __builtin_amdgcn_mfma_f32_16x16x32_bf16(af, bf1, acc[mi][1], 0, 0, 0);
      }
    }
    for (int mi = 0; mi < nmf; ++mi) {
      int mf = (mi == 0) ? wv : 8;
#pragma unroll
      for (int nf = 0; nf < 2; ++nf) {
        int ch = nf * 16 + lrow;
        float2 bb = bnp1[ch];
#pragma unroll
        for (int r = 0; r < 4; ++r) {
          int row = mf * 16 + (l >> 4) * 4 + r;
          float v = acc[mi][nf][r] * bb.x + bb.y;
          float h = v / (1.f + __expf(-v));
          __hip_bfloat16 hv = __float2bfloat16(h);
          h1T[row * 40 + ch] = *(short*)&hv;
        }
      }
    }
  }
  __syncthreads();
  {  // p2: 15 shifted MFMAs, N=16 (2 cols used); 8 m-frags = 1/wave
    f32x4 acc2 = (f32x4){0.f, 0.f, 0.f, 0.f};
    for (int koff = 0; koff < 15; ++koff) {
      s16x8 bf = *(const s16x8*)(wp2M + koff * 512 + l * 8);
      s16x8 af = *(const s16x8*)(&h1T[(wv * 16 + koff + lrow) * 40 + lk8]);
      acc2 = __builtin_amdgcn_mfma_f32_16x16x32_bf16(af, bf, acc2, 0, 0, 0);
    }
    int ch = lrow;
    if (ch < 2) {
      float pb = p2_b[ch];
      float nm = norm_mean[0];
#pragma unroll
      for (int r = 0; r < 4; ++r) {
        int t = t0 + wv * 16 + (l >> 4) * 4 + r;
        float a = acc2[r] + pb;
        float s = 1.f / (1.f + __expf(-a));
        if (ch == 0) wts[b * TN + t] = s;
        else         mvr[b * TN + t] = s * nm;
      }
    }
  }
}

// ========== K3: per-batch renorm + cumsum + first_t ==========
__global__ __launch_bounds__(256) void k3_scan(const float* __restrict__ mvr,
                                               float* __restrict__ poses,
                                               int* __restrict__ firstT) {
  int b = blockIdx.x, tid = threadIdx.x;
  __shared__ float csum[256];
  __shared__ int shlast;
  float v[16];
  const float* src = mvr + b * TN + tid * 16;
  float run = 0.f;
#pragma unroll
  for (int j = 0; j < 16; ++j) { run += src[j]; v[j] = run; }
  csum[tid] = run;
  __syncthreads();
  for (int off = 1; off < 256; off <<= 1) {
    float tv = (tid >= off) ? csum[tid - off] : 0.f;
    __syncthreads();
    csum[tid] += tv;
    __syncthreads();
  }
  float incl = csum[tid];
  float total = csum[255];
  float excl = incl - run;
  __syncthreads();
  float rn = total * (1.0f / 4096.0f);
  float inv = (rn > 1.0f) ? 1.0f / rn : 1.0f;
  float p16[16];
  float* pd = poses + b * TN + tid * 16;
#pragma unroll
  for (int j = 0; j < 16; ++j) { p16[j] = (excl + v[j]) * inv; pd[j] = p16[j]; }
  csum[tid] = p16[15];
  __syncthreads();
  int* ft = firstT + b * FTS;
  int prevf = (tid == 0) ? -1 : min((int)floorf(csum[tid - 1]), 4220);
  int f = prevf;
#pragma unroll
  for (int j = 0; j < 16; ++j) {
    f = min((int)floorf(p16[j]), 4220);
    for (int l = prevf + 1; l <= f; ++l) ft[l] = tid * 16 + j;
    prevf = f;
  }
  if (tid == 255) shlast = f;
  __syncthreads();
  for (int l = shlast + 1 + tid; l < FTS; l += 256) ft[l] = TN;
}

// ========== K4: gather pool v3 — register running-sums, 16-row tiles ==========
__global__ __launch_bounds__(256) void k4_gather(
    const __hip_bfloat16* __restrict__ featT, const float* __restrict__ wts,
    const float* __restrict__ poses, const int* __restrict__ firstT,
    float* __restrict__ out) {
  int d = blockIdx.x + 257 * blockIdx.y;         // 0..4111
  int w = (d & 7) * 514 + (d >> 3);              // XCD k owns b in [2k,2k+2), all lx
  int lx = w % 257, b = w / 257;
  int l0 = lx * 16;
  __shared__ float acc[16][259];
  int tid = threadIdx.x;
  for (int i = tid; i < 16 * 259; i += 256) ((float*)acc)[i] = 0.f;
  const int* ft = firstT + b * FTS;
  int ts = (l0 == 0) ? 0 : ft[l0 - 1];
  int te = ft[l0 + 16];
  __syncthreads();
  int c = tid;
  if (ts < te) {
    const float* pp = poses + b * TN;
    const float* wp = wts + b * TN;
    const __hip_bfloat16* fp = featT + (size_t)(b * TN) * 256 + c;
    float p_cur = pp[ts];
    float w_cur = wp[ts];
    float f_cur = __bfloat162float(fp[(size_t)ts * 256]);
    float S_lo = 0.f, S_hi = 0.f;
    int cur = (int)floorf(p_cur);
    for (int t = ts; t < te; ++t) {
      float p_nxt = 0.f, w_nxt = 0.f, f_nxt = 0.f;
      if (t + 1 < te) {                          // prefetch next iter
        p_nxt = pp[t + 1];
        w_nxt = wp[t + 1];
        f_nxt = __bfloat162float(fp[(size_t)(t + 1) * 256]);
      }
      int fi = (int)floorf(p_cur);
      if (fi < cur) fi = cur;                    // FP scan-boundary wobble guard
      if (fi != cur) {                           // wave-uniform advance
        int r = cur - l0;
        if (r >= 0 && r < 16) acc[r][c] = S_lo;  // row cur is final
        if (fi == cur + 1) {
          S_lo = S_hi;
        } else {                                 // jump (FP anomaly / init only)
          int r2 = cur + 1 - l0;
          if (r2 >= 0 && r2 < 16) acc[r2][c] = S_hi;
          S_lo = 0.f;
        }
        S_hi = 0.f;
        cur = fi;
      }
      float w2 = p_cur - (float)fi;
      float fw = f_cur * w_cur;
      S_lo = fmaf(1.f - w2, fw, S_lo);
      S_hi = fmaf(w2, fw, S_hi);
      p_cur = p_nxt; w_cur = w_nxt; f_cur = f_nxt;
    }
    int r = cur - l0;                            // final rows
    if (r >= 0 && r < 16) acc[r][c] = S_lo;
    int r2 = cur + 1 - l0;
    if (r2 >= 0 && r2 < 16) acc[r2][c] = S_hi;
  }
  __syncthreads();
  // dump: 16 consecutive lanes cover 16 l of one c-row -> coalesced 64B segments
  for (int i = tid; i < 4096; i += 256) {
    int c2 = i >> 4, r = i & 15;
    int l = l0 + r;
    if (l < LOUT) out[((size_t)b * 256 + c2) * LOUT + l] = acc[r][c2];
  }
}

// ======================= launch =======================
extern "C" void kernel_launch(void* const* d_in, const int* in_sizes, int n_in,
                              void* d_out, int out_size, void* d_ws, size_t ws_size,
                              hipStream_t stream) {
  const float* x       = (const float*)d_in[0];
  const float* conv1_w = (const float*)d_in[1];
  const float* bn1_g   = (const float*)d_in[2];
  const float* bn1_b   = (const float*)d_in[3];
  const float* bn1_m   = (const float*)d_in[4];
  const float* bn1_v   = (const float*)d_in[5];
  const float* w1x1    = (const float*)d_in[6];
  const float* p0_w    = (const float*)d_in[7];
  const float* p0_b    = (const float*)d_in[8];
  const float* p0g     = (const float*)d_in[9];
  const float* p0bb    = (const float*)d_in[10];
  const float* p0m     = (const float*)d_in[11];
  const float* p0v     = (const float*)d_in[12];
  const float* p1_w    = (const float*)d_in[13];
  const float* p1_b    = (const float*)d_in[14];
  const float* p1g     = (const float*)d_in[15];
  const float* p1bb    = (const float*)d_in[16];
  const float* p1m     = (const float*)d_in[17];
  const float* p1v     = (const float*)d_in[18];
  const float* p2_w    = (const float*)d_in[19];
  const float* p2_b    = (const float*)d_in[20];
  const float* nmean   = (const float*)d_in[21];

  char* ws = (char*)d_ws;
  __hip_bfloat16* featT = (__hip_bfloat16*)ws;
  short* wBpk   = (short*)(ws + 33554432);
  float4* bnp   = (float4*)(ws + 33816576);
  float* wp0T   = (float*)(ws + 33820672);
  short* wp1M   = (short*)(ws + 33828864);
  short* wp2M   = (short*)(ws + 33859584);
  float2* bnp0  = (float2*)(ws + 33874944);
  float2* bnp1  = (float2*)(ws + 33875200);
  float* xx     = (float*)(ws + 33890304);
  float* wts    = (float*)(ws + 34152448);
  float* mvr    = (float*)(ws + 34414592);
  float* poses  = (float*)(ws + 34676736);
  int*   firstT = (int*)  (ws + 34938880);
  float* out    = (float*)d_out;

  k0_prep<<<dim3(572), dim3(256), 0, stream>>>(
      conv1_w, p0_w, p1_w, p2_w, bn1_g, bn1_b, bn1_m, bn1_v,
      p0_b, p0g, p0bb, p0m, p0v, p1_b, p1g, p1bb, p1m, p1v,
      wBpk, bnp, wp0T, wp1M, wp2M, bnp0, bnp1);
  k1_mfma<<<dim3(4096), dim3(256), 0, stream>>>(x, w1x1, wBpk, bnp, featT, xx);
  k2_pred<<<dim3(32, 16), dim3(512), 0, stream>>>(xx, wp0T, bnp0, wp1M, bnp1,
                                                  wp2M, p2_b, nmean, wts, mvr);
  k3_scan<<<dim3(16), dim3(256), 0, stream>>>(mvr, poses, firstT);
  k4_gather<<<dim3(257, 16), dim3(256), 0, stream>>>(featT, wts, poses, firstT, out);
}

// Round 10
// 95.544 us; speedup vs baseline: 1.8632x; 1.0005x over previous
//
#include <hip/hip_runtime.h>
#include <hip/hip_bf16.h>

#define BB   16
#define CIN  256
#define TN   4096
#define LOUT 4110
#define FTS  4224   // first_t per-batch stride (ints)

typedef __attribute__((ext_vector_type(8))) short s16x8;
typedef __attribute__((ext_vector_type(4))) float f32x4;

// ---------------- workspace layout (bytes) ----------------
// featT  bf16 [B][T][256]        0          (33554432)
// wBpk   bf16 fragment-packed    33554432   (262144)  -> 33816576
// bnp    float4[256]             33816576   (4096)    -> 33820672
// wp0T   f32  [62][32]           33820672   (8192)    -> 33828864
// wp1M   bf16 frag-packed p1     33828864   (30720)   -> 33859584
// wp2M   bf16 frag-packed p2     33859584   (15360)   -> 33874944
// bnp0   float2[32]              33874944   (256)     -> 33875200
// bnp1   float2[32]              33875200   (256)     -> 33875456
// xx     f32  [B][T]             33890304
// wts    f32  [B][T]             34152448
// mvr    f32  [B][T]             34414592
// poses  f32  [B][T]             34676736
// firstT int  [B][4224]          34938880   (end 35209216)

// ======================= K0: weight prep =======================
__global__ __launch_bounds__(256) void k0_prep(
    const float* __restrict__ conv1_w, const float* __restrict__ p0_w,
    const float* __restrict__ p1_w, const float* __restrict__ p2_w,
    const float* __restrict__ bn1_g, const float* __restrict__ bn1_b,
    const float* __restrict__ bn1_m, const float* __restrict__ bn1_v,
    const float* __restrict__ p0_b, const float* __restrict__ p0g,
    const float* __restrict__ p0bb, const float* __restrict__ p0m,
    const float* __restrict__ p0v,
    const float* __restrict__ p1_b, const float* __restrict__ p1g,
    const float* __restrict__ p1bb, const float* __restrict__ p1m,
    const float* __restrict__ p1v,
    short* __restrict__ wBpk, float4* __restrict__ bnp,
    float* __restrict__ wp0T, short* __restrict__ wp1M,
    short* __restrict__ wp2M, float2* __restrict__ bnp0,
    float2* __restrict__ bnp1) {
  int bid = blockIdx.x, tid = threadIdx.x;
  if (bid < 512) {
    // wBpk flat: ((n16*8 + ks)*64 + l)*8 + i ; value = Wpacked[n16*16+(l&15)][ks*32+(l>>4)*8+i]
    int e = bid * 256 + tid;               // 0..131071
    int i = e & 7, l = (e >> 3) & 63, ks = (e >> 9) & 7, n16 = e >> 12;
    int n = n16 * 16 + (l & 15);           // packed col 0..511
    int j = n & 63;
    int co = (j < 32) ? ((n >> 6) * 32 + j) : (256 + (n >> 6) * 32 + (j - 32));
    int ci = ks * 32 + (l >> 4) * 8 + i;
    __hip_bfloat16 hv = __float2bfloat16(conv1_w[co * 256 + ci]);
    wBpk[e] = *(short*)&hv;
  } else {
    int idx = (bid - 512) * 256 + tid;     // 0..15359
    if (idx < 1984) {
      int ch = idx & 31, rem = idx >> 5;
      int ic = rem / 31, k = rem % 31;
      wp0T[idx] = p0_w[(ch * 2 + ic) * 31 + k];
    }
    {  // wp1M: idx bits [0:3)=i, [3:9)=l, [9)=nf, [10:..)=koff
      int i = idx & 7, l = (idx >> 3) & 63, nf = (idx >> 9) & 1, koff = idx >> 10;
      int ch = nf * 16 + (l & 15), ic = (l >> 4) * 8 + i;
      __hip_bfloat16 hv = __float2bfloat16(p1_w[(ch * 32 + ic) * 15 + koff]);
      wp1M[idx] = *(short*)&hv;
    }
    if (idx < 7680) {  // wp2M: bits [0:3)=i, [3:9)=l, [9:..)=koff
      int i = idx & 7, l = (idx >> 3) & 63, koff = idx >> 9;
      int n = l & 15, ic = (l >> 4) * 8 + i;
      float v = (n < 2) ? p2_w[(n * 32 + ic) * 15 + koff] : 0.f;
      __hip_bfloat16 hv = __float2bfloat16(v);
      wp2M[idx] = *(short*)&hv;
    }
    if (idx < 32) {
      int ch = idx;
      float sc = p0g[ch] * rsqrtf(p0v[ch] + 1e-5f);
      bnp0[ch] = make_float2(sc, (p0_b[ch] - p0m[ch]) * sc + p0bb[ch]);
    }
    if (idx >= 32 && idx < 64) {
      int ch = idx - 32;
      float sc = p1g[ch] * rsqrtf(p1v[ch] + 1e-5f);
      bnp1[ch] = make_float2(sc, (p1_b[ch] - p1m[ch]) * sc + p1bb[ch]);
    }
    if (idx < 256) {
      int c = idx;
      float sa = bn1_g[c] * rsqrtf(bn1_v[c] + 1e-3f);
      float ba = bn1_b[c] - bn1_m[c] * sa;
      float sg = bn1_g[c + 256] * rsqrtf(bn1_v[c + 256] + 1e-3f);
      float bg = bn1_b[c + 256] - bn1_m[c + 256] * sg;
      bnp[c] = make_float4(sa, ba, sg, bg);
    }
  }
}

// ========== K1 v5: v4 geometry + ILP restructure (issue-early, prefetch B) ==========
// grid 4096 flat: bid -> xcd = bid&7; k = bid>>3; nblk = k&3; T = (k>>2)*8 + xcd.
// Block: 256 thr = 4 waves; tile 64t x 128n x 256k. LDS hb[64][132] u32 (bf16
// pairs, cvt once). Phase A: issue ALL 16 staging float4 loads into registers;
// Phase B: convert+write+xx. B-frags (ks=0) issued before the barrier; inside the
// fully-unrolled ks loop, ks+1 B-frags issue before the MFMA cluster.
__global__ __launch_bounds__(256, 4) void k1_mfma(
    const float* __restrict__ x, const float* __restrict__ w1x1,
    const short* __restrict__ wBpk, const float4* __restrict__ bnp,
    __hip_bfloat16* __restrict__ featT, float* __restrict__ xx) {
  int bid = blockIdx.x;
  int xcd = bid & 7, kk = bid >> 3;
  int nblk = kk & 3;
  int T = (kk >> 2) * 8 + xcd;           // 0..1023
  int ty = T & 63, b = T >> 6;
  int t0 = ty * 64;
  __shared__ __align__(16) unsigned int hb[64 * 132];
  __shared__ float xws[4][68];
  int tid = threadIdx.x;
  int l = tid & 63, wv = tid >> 6;
  int tq = l & 15, Cb = l >> 4;
  int q = (tq >> 1) & 3;
  const float* xb = x + (size_t)b * (CIN * TN) + t0 + 4 * tq;

  // phase A: issue all 16 staging loads (64 VGPR of data in flight)
  float4 f0[8], f1[8];
#pragma unroll
  for (int iter = 0; iter < 8; ++iter) {
    int C = 4 * wv + Cb + 16 * iter;     // cpair 0..127
    int ci = 2 * C;
    f0[iter] = *(const float4*)(xb + (size_t)ci * TN);
    f1[iter] = *(const float4*)(xb + (size_t)(ci + 1) * TN);
  }

  // phase B: convert once, LDS-write (XOR-swizzled), xx partials (same order as v4)
  float xxp[4] = {0.f, 0.f, 0.f, 0.f};
#pragma unroll
  for (int iter = 0; iter < 8; ++iter) {
    int C = 4 * wv + Cb + 16 * iter;
    int ci = 2 * C;
    float w0 = w1x1[ci], w1 = w1x1[ci + 1];
    unsigned int* dst = hb + (C ^ (q << 2));
    float fa[4] = {f0[iter].x, f0[iter].y, f0[iter].z, f0[iter].w};
    float fb[4] = {f1[iter].x, f1[iter].y, f1[iter].z, f1[iter].w};
#pragma unroll
    for (int r = 0; r < 4; ++r) {
      __hip_bfloat16 lo = __float2bfloat16(fa[r]);
      __hip_bfloat16 hi = __float2bfloat16(fb[r]);
      unsigned int pk = (unsigned int)(*(unsigned short*)&lo) |
                        ((unsigned int)(*(unsigned short*)&hi) << 16);
      dst[(4 * tq + r) * 132] = pk;
      xxp[r] = fmaf(w0, fa[r], fmaf(w1, fb[r], xxp[r]));
    }
  }
#pragma unroll
  for (int r = 0; r < 4; ++r) {          // reduce over Cb (lanes stride 16)
    xxp[r] += __shfl_xor(xxp[r], 16);
    xxp[r] += __shfl_xor(xxp[r], 32);
  }
  if (Cb == 0) {
#pragma unroll
    for (int r = 0; r < 4; ++r) xws[wv][4 * tq + r] = xxp[r];
  }

  // issue ks=0 B-frags BEFORE the barrier (latency hides under it)
  int lr = l & 15, lk = l >> 4;
  int glu = 2 * nblk + (wv >> 1), sub = wv & 1;
  int n16a = glu * 4 + sub;              // partner frag = n16a + 2 (GLU pair)
  const short* wrow = wBpk + (size_t)l * 8;
  s16x8 bf0 = *(const s16x8*)(wrow + (size_t)n16a * 4096);
  s16x8 bf1 = *(const s16x8*)(wrow + (size_t)(n16a + 2) * 4096);

  __syncthreads();
  if (tid < 64)
    xx[b * TN + t0 + tid] = xws[0][tid] + xws[1][tid] + xws[2][tid] + xws[3][tid];

  f32x4 acc[4][2];
#pragma unroll
  for (int i = 0; i < 4; ++i) {
    acc[i][0] = (f32x4){0.f, 0.f, 0.f, 0.f};
    acc[i][1] = (f32x4){0.f, 0.f, 0.f, 0.f};
  }

#pragma unroll
  for (int ks = 0; ks < 8; ++ks) {
    // A-frags for this ks (LDS, swizzled)
    s16x8 af[4];
#pragma unroll
    for (int mf = 0; mf < 4; ++mf) {
      int row = mf * 16 + lr;
      int grp = ks * 4 + lk;
      int qr = (row >> 3) & 3;
      af[mf] = *(const s16x8*)(hb + row * 132 + ((grp ^ qr) << 2));
    }
    // prefetch ks+1 B-frags before the MFMA cluster
    s16x8 nbf0, nbf1;
    if (ks < 7) {
      nbf0 = *(const s16x8*)(wrow + (size_t)n16a * 4096 + (ks + 1) * 512);
      nbf1 = *(const s16x8*)(wrow + (size_t)(n16a + 2) * 4096 + (ks + 1) * 512);
    }
#pragma unroll
    for (int mf = 0; mf < 4; ++mf) {
      acc[mf][0] = __builtin_amdgcn_mfma_f32_16x16x32_bf16(af[mf], bf0, acc[mf][0], 0, 0, 0);
      acc[mf][1] = __builtin_amdgcn_mfma_f32_16x16x32_bf16(af[mf], bf1, acc[mf][1], 0, 0, 0);
    }
    if (ks < 7) { bf0 = nbf0; bf1 = nbf1; }
  }

  // epilogue: BN + GLU (frag n16a col j pairs with n16a+2 col j+32, same lane)
  int c = glu * 32 + sub * 16 + lr;
  float4 bn = bnp[c];
#pragma unroll
  for (int mf = 0; mf < 4; ++mf) {
#pragma unroll
    for (int r = 0; r < 4; ++r) {
      float a = acc[mf][0][r], g = acc[mf][1][r];
      float av = fmaf(a, bn.x, bn.y);
      float gv = fmaf(g, bn.z, bn.w);
      float fv = av / (1.f + __expf(-gv));
      int t = t0 + mf * 16 + lk * 4 + r;
      featT[((size_t)b * TN + t) * 256 + c] = __float2bfloat16(fv);
    }
  }
}

// ========== K2: fused predictor; p0 = VALU f32, p1/p2 = MFMA bf16 ==========
// grid (32 t-tiles of 128, 16 b), 512 thr = 8 waves.
__global__ __launch_bounds__(512) void k2_pred(
    const float* __restrict__ xx,
    const float* __restrict__ wp0T, const float2* __restrict__ bnp0,
    const short* __restrict__ wp1M, const float2* __restrict__ bnp1,
    const short* __restrict__ wp2M, const float* __restrict__ p2_b,
    const float* __restrict__ norm_mean,
    float* __restrict__ wts, float* __restrict__ mvr) {
  int t0 = blockIdx.x * 128;
  int b = blockIdx.y;
  __shared__ float xin[2][192];     // t = t0-29+q, valid q<186
  __shared__ short h0T[160 * 40];
  __shared__ short h1T[144 * 40];
  int tid = threadIdx.x;
  for (int q = tid; q < 192; q += 512) {
    int t = t0 - 29 + q;
    float v = (q < 186 && t >= 0 && t < TN) ? xx[b * TN + t] : 0.f;
    xin[0][q] = v;
    xin[1][q] = v * v;
  }
  __syncthreads();
  {  // p0: K=31, 2 in-ch, f32 VALU; thread (ch, tq) -> 12 outputs
    int ch = tid & 31, tq = tid >> 5;    // tq 0..15
    int i0 = tq * 12;
    if (i0 < 156) {
      float2 bb0 = bnp0[ch];
      float a0[12];
#pragma unroll
      for (int j = 0; j < 12; ++j) a0[j] = 0.f;
#pragma unroll
      for (int ic = 0; ic < 2; ++ic) {
        float rr[44];
#pragma unroll
        for (int q = 0; q < 11; ++q) {
          float4 t4 = *(const float4*)(&xin[ic][i0 + q * 4]);
          rr[q * 4 + 0] = t4.x; rr[q * 4 + 1] = t4.y;
          rr[q * 4 + 2] = t4.z; rr[q * 4 + 3] = t4.w;
        }
#pragma unroll
        for (int k = 0; k < 31; ++k) {
          float w = wp0T[(ic * 31 + k) * 32 + ch];
#pragma unroll
          for (int j = 0; j < 12; ++j) a0[j] = fmaf(w, rr[j + k], a0[j]);
        }
      }
#pragma unroll
      for (int j = 0; j < 12; ++j) {
        int i = i0 + j;
        if (i < 156) {
          float v = a0[j] * bb0.x + bb0.y;
          float h = v / (1.f + __expf(-v));
          __hip_bfloat16 hv = __float2bfloat16(h);
          h0T[i * 40 + ch] = *(short*)&hv;
        }
      }
    }
    if (tid < 128) h0T[(156 + (tid >> 5)) * 40 + (tid & 31)] = 0;  // zero pad rows
  }
  __syncthreads();
  int l = tid & 63, wv = tid >> 6;
  int lrow = l & 15, lk8 = (l >> 4) * 8;
  {  // p1: 15 shifted MFMAs (K=32=ic); 9 m-frags over 8 waves (wave0 gets 2)
    f32x4 acc[2][2];
#pragma unroll
    for (int i = 0; i < 2; ++i)
#pragma unroll
      for (int j = 0; j < 2; ++j) acc[i][j] = (f32x4){0.f, 0.f, 0.f, 0.f};
    int nmf = (wv == 0) ? 2 : 1;
    for (int koff = 0; koff < 15; ++koff) {
      const short* bp = wp1M + koff * 1024;
      s16x8 bf0 = *(const s16x8*)(bp + l * 8);
      s16x8 bf1 = *(const s16x8*)(bp + 512 + l * 8);
      for (int mi = 0; mi < nmf; ++mi) {
        int mf = (mi == 0) ? wv : 8;
        s16x8 af = *(const s16x8*)(&h0T[(mf * 16 + koff + lrow) * 40 + lk8]);
        acc[mi][0] = __builtin_amdgcn_mfma_f32_16x16x32_bf16(af, bf0, acc[mi][0], 0, 0, 0);
        acc[mi][1] = __builtin_amdgcn_mfma_f32_16x16x32_bf16(af, bf1, acc[mi][1], 0, 0, 0);
      }
    }
    for (int mi = 0; mi < nmf; ++mi) {
      int mf = (mi == 0) ? wv : 8;
#pragma unroll
      for (int nf = 0; nf < 2; ++nf) {
        int ch = nf * 16 + lrow;
        float2 bb = bnp1[ch];
#pragma unroll
        for (int r = 0; r < 4; ++r) {
          int row = mf * 16 + (l >> 4) * 4 + r;
          float v = acc[mi][nf][r] * bb.x + bb.y;
          float h = v / (1.f + __expf(-v));
          __hip_bfloat16 hv = __float2bfloat16(h);
          h1T[row * 40 + ch] = *(short*)&hv;
        }
      }
    }
  }
  __syncthreads();
  {  // p2: 15 shifted MFMAs, N=16 (2 cols used); 8 m-frags = 1/wave
    f32x4 acc2 = (f32x4){0.f, 0.f, 0.f, 0.f};
    for (int koff = 0; koff < 15; ++koff) {
      s16x8 bf = *(const s16x8*)(wp2M + koff * 512 + l * 8);
      s16x8 af = *(const s16x8*)(&h1T[(wv * 16 + koff + lrow) * 40 + lk8]);
      acc2 = __builtin_amdgcn_mfma_f32_16x16x32_bf16(af, bf, acc2, 0, 0, 0);
    }
    int ch = lrow;
    if (ch < 2) {
      float pb = p2_b[ch];
      float nm = norm_mean[0];
#pragma unroll
      for (int r = 0; r < 4; ++r) {
        int t = t0 + wv * 16 + (l >> 4) * 4 + r;
        float a = acc2[r] + pb;
        float s = 1.f / (1.f + __expf(-a));
        if (ch == 0) wts[b * TN + t] = s;
        else         mvr[b * TN + t] = s * nm;
      }
    }
  }
}

// ========== K3: per-batch renorm + cumsum + first_t ==========
__global__ __launch_bounds__(256) void k3_scan(const float* __restrict__ mvr,
                                               float* __restrict__ poses,
                                               int* __restrict__ firstT) {
  int b = blockIdx.x, tid = threadIdx.x;
  __shared__ float csum[256];
  __shared__ int shlast;
  float v[16];
  const float* src = mvr + b * TN + tid * 16;
  float run = 0.f;
#pragma unroll
  for (int j = 0; j < 16; ++j) { run += src[j]; v[j] = run; }
  csum[tid] = run;
  __syncthreads();
  for (int off = 1; off < 256; off <<= 1) {
    float tv = (tid >= off) ? csum[tid - off] : 0.f;
    __syncthreads();
    csum[tid] += tv;
    __syncthreads();
  }
  float incl = csum[tid];
  float total = csum[255];
  float excl = incl - run;
  __syncthreads();
  float rn = total * (1.0f / 4096.0f);
  float inv = (rn > 1.0f) ? 1.0f / rn : 1.0f;
  float p16[16];
  float* pd = poses + b * TN + tid * 16;
#pragma unroll
  for (int j = 0; j < 16; ++j) { p16[j] = (excl + v[j]) * inv; pd[j] = p16[j]; }
  csum[tid] = p16[15];
  __syncthreads();
  int* ft = firstT + b * FTS;
  int prevf = (tid == 0) ? -1 : min((int)floorf(csum[tid - 1]), 4220);
  int f = prevf;
#pragma unroll
  for (int j = 0; j < 16; ++j) {
    f = min((int)floorf(p16[j]), 4220);
    for (int l = prevf + 1; l <= f; ++l) ft[l] = tid * 16 + j;
    prevf = f;
  }
  if (tid == 255) shlast = f;
  __syncthreads();
  for (int l = shlast + 1 + tid; l < FTS; l += 256) ft[l] = TN;
}

// ========== K4: gather pool v3 — register running-sums, 16-row tiles ==========
__global__ __launch_bounds__(256) void k4_gather(
    const __hip_bfloat16* __restrict__ featT, const float* __restrict__ wts,
    const float* __restrict__ poses, const int* __restrict__ firstT,
    float* __restrict__ out) {
  int d = blockIdx.x + 257 * blockIdx.y;         // 0..4111
  int w = (d & 7) * 514 + (d >> 3);              // XCD k owns b in [2k,2k+2), all lx
  int lx = w % 257, b = w / 257;
  int l0 = lx * 16;
  __shared__ float acc[16][259];
  int tid = threadIdx.x;
  for (int i = tid; i < 16 * 259; i += 256) ((float*)acc)[i] = 0.f;
  const int* ft = firstT + b * FTS;
  int ts = (l0 == 0) ? 0 : ft[l0 - 1];
  int te = ft[l0 + 16];
  __syncthreads();
  int c = tid;
  if (ts < te) {
    const float* pp = poses + b * TN;
    const float* wp = wts + b * TN;
    const __hip_bfloat16* fp = featT + (size_t)(b * TN) * 256 + c;
    float p_cur = pp[ts];
    float w_cur = wp[ts];
    float f_cur = __bfloat162float(fp[(size_t)ts * 256]);
    float S_lo = 0.f, S_hi = 0.f;
    int cur = (int)floorf(p_cur);
    for (int t = ts; t < te; ++t) {
      float p_nxt = 0.f, w_nxt = 0.f, f_nxt = 0.f;
      if (t + 1 < te) {                          // prefetch next iter
        p_nxt = pp[t + 1];
        w_nxt = wp[t + 1];
        f_nxt = __bfloat162float(fp[(size_t)(t + 1) * 256]);
      }
      int fi = (int)floorf(p_cur);
      if (fi < cur) fi = cur;                    // FP scan-boundary wobble guard
      if (fi != cur) {                           // wave-uniform advance
        int r = cur - l0;
        if (r >= 0 && r < 16) acc[r][c] = S_lo;  // row cur is final
        if (fi == cur + 1) {
          S_lo = S_hi;
        } else {                                 // jump (FP anomaly / init only)
          int r2 = cur + 1 - l0;
          if (r2 >= 0 && r2 < 16) acc[r2][c] = S_hi;
          S_lo = 0.f;
        }
        S_hi = 0.f;
        cur = fi;
      }
      float w2 = p_cur - (float)fi;
      float fw = f_cur * w_cur;
      S_lo = fmaf(1.f - w2, fw, S_lo);
      S_hi = fmaf(w2, fw, S_hi);
      p_cur = p_nxt; w_cur = w_nxt; f_cur = f_nxt;
    }
    int r = cur - l0;                            // final rows
    if (r >= 0 && r < 16) acc[r][c] = S_lo;
    int r2 = cur + 1 - l0;
    if (r2 >= 0 && r2 < 16) acc[r2][c] = S_hi;
  }
  __syncthreads();
  // dump: 16 consecutive lanes cover 16 l of one c-row -> coalesced 64B segments
  for (int i = tid; i < 4096; i += 256) {
    int c2 = i >> 4, r = i & 15;
    int l = l0 + r;
    if (l < LOUT) out[((size_t)b * 256 + c2) * LOUT + l] = acc[r][c2];
  }
}

// ======================= launch =======================
extern "C" void kernel_launch(void* const* d_in, const int* in_sizes, int n_in,
                              void* d_out, int out_size, void* d_ws, size_t ws_size,
                              hipStream_t stream) {
  const float* x       = (const float*)d_in[0];
  const float* conv1_w = (const float*)d_in[1];
  const float* bn1_g   = (const float*)d_in[2];
  const float* bn1_b   = (const float*)d_in[3];
  const float* bn1_m   = (const float*)d_in[4];
  const float* bn1_v   = (const float*)d_in[5];
  const float* w1x1    = (const float*)d_in[6];
  const float* p0_w    = (const float*)d_in[7];
  const float* p0_b    = (const float*)d_in[8];
  const float* p0g     = (const float*)d_in[9];
  const float* p0bb    = (const float*)d_in[10];
  const float* p0m     = (const float*)d_in[11];
  const float* p0v     = (const float*)d_in[12];
  const float* p1_w    = (const float*)d_in[13];
  const float* p1_b    = (const float*)d_in[14];
  const float* p1g     = (const float*)d_in[15];
  const float* p1bb    = (const float*)d_in[16];
  const float* p1m     = (const float*)d_in[17];
  const float* p1v     = (const float*)d_in[18];
  const float* p2_w    = (const float*)d_in[19];
  const float* p2_b    = (const float*)d_in[20];
  const float* nmean   = (const float*)d_in[21];

  char* ws = (char*)d_ws;
  __hip_bfloat16* featT = (__hip_bfloat16*)ws;
  short* wBpk   = (short*)(ws + 33554432);
  float4* bnp   = (float4*)(ws + 33816576);
  float* wp0T   = (float*)(ws + 33820672);
  short* wp1M   = (short*)(ws + 33828864);
  short* wp2M   = (short*)(ws + 33859584);
  float2* bnp0  = (float2*)(ws + 33874944);
  float2* bnp1  = (float2*)(ws + 33875200);
  float* xx     = (float*)(ws + 33890304);
  float* wts    = (float*)(ws + 34152448);
  float* mvr    = (float*)(ws + 34414592);
  float* poses  = (float*)(ws + 34676736);
  int*   firstT = (int*)  (ws + 34938880);
  float* out    = (float*)d_out;

  k0_prep<<<dim3(572), dim3(256), 0, stream>>>(
      conv1_w, p0_w, p1_w, p2_w, bn1_g, bn1_b, bn1_m, bn1_v,
      p0_b, p0g, p0bb, p0m, p0v, p1_b, p1g, p1bb, p1m, p1v,
      wBpk, bnp, wp0T, wp1M, wp2M, bnp0, bnp1);
  k1_mfma<<<dim3(4096), dim3(256), 0, stream>>>(x, w1x1, wBpk, bnp, featT, xx);
  k2_pred<<<dim3(32, 16), dim3(512), 0, stream>>>(xx, wp0T, bnp0, wp1M, bnp1,
                                                  wp2M, p2_b, nmean, wts, mvr);
  k3_scan<<<dim3(16), dim3(256), 0, stream>>>(mvr, poses, firstT);
  k4_gather<<<dim3(257, 16), dim3(256), 0, stream>>>(featT, wts, poses, firstT, out);
}